// Round 1
// baseline (16730.858 us; speedup 1.0000x reference)
//
#include <hip/hip_runtime.h>
#include <math.h>

static constexpr int D = 128;
static constexpr int NHEAD = 8;
static constexpr int HDIM = 16;

__device__ __forceinline__ float gelu_f(float x) {
  return 0.5f * x * (1.0f + erff(x * 0.7071067811865476f));
}
// order-preserving float->uint encoding for atomicMax on floats
__device__ __forceinline__ unsigned enc_f(float f) {
  unsigned u = __float_as_uint(f);
  return (u & 0x80000000u) ? ~u : (u | 0x80000000u);
}
__device__ __forceinline__ float dec_f(unsigned u) {
  return (u & 0x80000000u) ? __uint_as_float(u & 0x7fffffffu) : __uint_as_float(~u);
}
#define ENC_NEG_INF 0x007FFFFFu  // enc(-inf)

// ---------------- elementwise / init ----------------
__global__ void k_init_h(const float* __restrict__ a, const float* __restrict__ b,
                         const float* __restrict__ c, float* __restrict__ h, int n) {
  int i = blockIdx.x * 256 + threadIdx.x;
  if (i < n) h[i] = a[i] + b[i] + c[i];
}

__global__ void k_init_acc_bias(const float* __restrict__ bias, float* __restrict__ acc, int nd) {
  int i = blockIdx.x * 256 + threadIdx.x;
  if (i < nd) {
    int d = i & (D - 1);
    acc[i] = bias[d] + bias[D + d] + bias[2 * D + d] + bias[3 * D + d];
  }
}

__global__ void k_zero(float* __restrict__ p, int n) {
  int i = blockIdx.x * 256 + threadIdx.x;
  if (i < n) p[i] = 0.f;
}

__global__ void k_init_ms(unsigned* __restrict__ m, float* __restrict__ s, int n) {
  int i = blockIdx.x * 256 + threadIdx.x;
  if (i < n) { m[i] = ENC_NEG_INF; s[i] = 0.f; }
}

// ---------------- GEMM: C[N,128] = op(A)[N,128] @ W[128,128] (+bias) ----------------
// BM=64 rows/block, 256 threads, full W staged in LDS, 4x8 register tile per thread.
template <bool GELU_A, bool BIAS>
__global__ __launch_bounds__(256) void k_gemm128(const float* __restrict__ A,
                                                 const float* __restrict__ W,
                                                 const float* __restrict__ bias,
                                                 float* __restrict__ C, int N) {
  __shared__ float Ws[D * D];      // 64 KB
  __shared__ float As[64 * 132];   // padded rows to break bank conflicts
  const int tid = threadIdx.x;
  const int row0 = blockIdx.x * 64;
  const int nrows = N - row0;  // > 0 by grid construction

  const float4* W4 = (const float4*)W;
  float4* Ws4 = (float4*)Ws;
#pragma unroll
  for (int i = 0; i < 16; ++i) Ws4[tid + 256 * i] = W4[tid + 256 * i];

  for (int i = tid; i < 64 * 32; i += 256) {
    int r = i >> 5, c = i & 31;
    float4 v = make_float4(0.f, 0.f, 0.f, 0.f);
    if (r < nrows) v = ((const float4*)A)[(size_t)(row0 + r) * 32 + c];
    if (GELU_A) { v.x = gelu_f(v.x); v.y = gelu_f(v.y); v.z = gelu_f(v.z); v.w = gelu_f(v.w); }
    float* dp = &As[r * 132 + c * 4];
    dp[0] = v.x; dp[1] = v.y; dp[2] = v.z; dp[3] = v.w;
  }
  __syncthreads();

  const int cg = tid & 15, rg = tid >> 4;
  const int c0 = cg * 8, r0 = rg * 4;
  float acc[4][8];
#pragma unroll
  for (int j = 0; j < 4; ++j)
#pragma unroll
    for (int c = 0; c < 8; ++c) acc[j][c] = 0.f;

#pragma unroll 4
  for (int k = 0; k < D; ++k) {
    float4 b0 = *(const float4*)&Ws[k * D + c0];
    float4 b1 = *(const float4*)&Ws[k * D + c0 + 4];
    float a_[4];
#pragma unroll
    for (int j = 0; j < 4; ++j) a_[j] = As[(r0 + j) * 132 + k];
#pragma unroll
    for (int j = 0; j < 4; ++j) {
      acc[j][0] += a_[j] * b0.x; acc[j][1] += a_[j] * b0.y;
      acc[j][2] += a_[j] * b0.z; acc[j][3] += a_[j] * b0.w;
      acc[j][4] += a_[j] * b1.x; acc[j][5] += a_[j] * b1.y;
      acc[j][6] += a_[j] * b1.z; acc[j][7] += a_[j] * b1.w;
    }
  }

#pragma unroll
  for (int j = 0; j < 4; ++j) {
    int r = r0 + j;
    if (r < nrows) {
      float o[8];
#pragma unroll
      for (int c = 0; c < 8; ++c) o[c] = acc[j][c] + (BIAS ? bias[c0 + c] : 0.f);
      float4* Cp = (float4*)&C[(size_t)(row0 + r) * D + c0];
      Cp[0] = make_float4(o[0], o[1], o[2], o[3]);
      Cp[1] = make_float4(o[4], o[5], o[6], o[7]);
    }
  }
}

// ---------------- GAT: per-node attention coefficients ----------------
__global__ void k_alar(const float* __restrict__ xw, const float* __restrict__ as_,
                       const float* __restrict__ ad_, float* __restrict__ al,
                       float* __restrict__ ar, int N) {
  int i = blockIdx.x * 256 + threadIdx.x;
  if (i >= N * NHEAD) return;
  int n = i >> 3, h = i & 7;
  const float4* x4 = (const float4*)(xw + (size_t)n * D + h * HDIM);
  const float4* s4 = (const float4*)(as_ + h * HDIM);
  const float4* d4 = (const float4*)(ad_ + h * HDIM);
  float sa = 0.f, sd = 0.f;
#pragma unroll
  for (int j = 0; j < 4; ++j) {
    float4 x = x4[j], s = s4[j], d = d4[j];
    sa += x.x * s.x + x.y * s.y + x.z * s.z + x.w * s.w;
    sd += x.x * d.x + x.y * d.y + x.z * d.z + x.w * d.w;
  }
  al[i] = sa; ar[i] = sd;
}

__device__ __forceinline__ void gat_edge(const int* ei, int E, int e, int& src, int& dst) {
  if (e < E) { src = ei[e]; dst = ei[E + e]; } else { src = dst = e - E; }  // self-loops appended
}

__global__ void k_gat_p1(const int* __restrict__ ei, int E, int N,
                         const float* __restrict__ al, const float* __restrict__ ar,
                         unsigned* __restrict__ m) {
  int i = blockIdx.x * 256 + threadIdx.x;
  if (i >= (E + N) * NHEAD) return;
  int e = i >> 3, h = i & 7, src, dst;
  gat_edge(ei, E, e, src, dst);
  float x = al[src * 8 + h] + ar[dst * 8 + h];
  x = x >= 0.f ? x : 0.2f * x;
  atomicMax(&m[dst * 8 + h], enc_f(x));
}

__global__ void k_gat_p2(const int* __restrict__ ei, int E, int N,
                         const float* __restrict__ al, const float* __restrict__ ar,
                         const unsigned* __restrict__ m, float* __restrict__ s) {
  int i = blockIdx.x * 256 + threadIdx.x;
  if (i >= (E + N) * NHEAD) return;
  int e = i >> 3, h = i & 7, src, dst;
  gat_edge(ei, E, e, src, dst);
  float x = al[src * 8 + h] + ar[dst * 8 + h];
  x = x >= 0.f ? x : 0.2f * x;
  float mv = dec_f(m[dst * 8 + h]);
  if (!(mv > -3.0e38f)) mv = 0.f;
  atomicAdd(&s[dst * 8 + h], expf(x - mv));
}

__global__ void k_gat_p3(const int* __restrict__ ei, int E, int N,
                         const float* __restrict__ al, const float* __restrict__ ar,
                         const unsigned* __restrict__ m, const float* __restrict__ s,
                         const float* __restrict__ xw, float* __restrict__ acc) {
  int i = blockIdx.x * 256 + threadIdx.x;
  if (i >= (E + N) * NHEAD) return;
  int e = i >> 3, h = i & 7, src, dst;
  gat_edge(ei, E, e, src, dst);
  float x = al[src * 8 + h] + ar[dst * 8 + h];
  x = x >= 0.f ? x : 0.2f * x;
  float mv = dec_f(m[dst * 8 + h]);
  if (!(mv > -3.0e38f)) mv = 0.f;
  float p = expf(x - mv);
  float sv = s[dst * 8 + h];
  float w = p / (sv > 0.f ? sv : 1.f);
  const float4* xs = (const float4*)(xw + (size_t)src * D + h * HDIM);
  float* o = acc + (size_t)dst * D + h * HDIM;
#pragma unroll
  for (int j = 0; j < 4; ++j) {
    float4 v = xs[j];
    atomicAdd(o + j * 4 + 0, v.x * w);
    atomicAdd(o + j * 4 + 1, v.y * w);
    atomicAdd(o + j * 4 + 2, v.z * w);
    atomicAdd(o + j * 4 + 3, v.w * w);
  }
}

// ---------------- fused residual + RMSNorm + GELU ----------------
// MIX: o = beta*o + (1-beta)*h first (HGT skip). One wave per row.
template <bool MIX>
__global__ __launch_bounds__(256) void k_norm(const float* __restrict__ hin,
                                              const float* __restrict__ o_,
                                              const float* __restrict__ g,
                                              const float* __restrict__ skip,
                                              float* __restrict__ hout, int N) {
  int w = threadIdx.x >> 6, lane = threadIdx.x & 63;
  int row = blockIdx.x * 4 + w;
  if (row >= N) return;
  size_t base = (size_t)row * D;
  float h0 = hin[base + lane], h1 = hin[base + 64 + lane];
  float o0 = o_[base + lane], o1 = o_[base + 64 + lane];
  if (MIX) {
    float beta = 1.f / (1.f + expf(-skip[0]));
    o0 = beta * o0 + (1.f - beta) * h0;
    o1 = beta * o1 + (1.f - beta) * h1;
  }
  float ss = o0 * o0 + o1 * o1;
#pragma unroll
  for (int msk = 1; msk < 64; msk <<= 1) ss += __shfl_xor(ss, msk, 64);
  float r = rsqrtf(ss * (1.f / 128.f) + 1e-6f);
  float y0 = h0 + g[lane] * o0 * r;
  float y1 = h1 + g[64 + lane] * o1 * r;
  hout[base + lane] = gelu_f(y0);
  hout[base + 64 + lane] = gelu_f(y1);
}

// ---------------- HGT ----------------
__global__ __launch_bounds__(256) void k_hgt_pA(const int* __restrict__ ei, int E,
                                                const float* __restrict__ kb,
                                                const float* __restrict__ qb,
                                                const float* __restrict__ rel,
                                                const float* __restrict__ prel_t,
                                                float* __restrict__ att,
                                                unsigned* __restrict__ m) {
  __shared__ float ws[8 * 257];  // arel[t], padded per-head to avoid bank conflicts
  for (int i = threadIdx.x; i < 2048; i += 256) ws[(i >> 8) * 257 + (i & 255)] = rel[i];
  __syncthreads();
  int i = blockIdx.x * 256 + threadIdx.x;
  if (i >= E * NHEAD) return;
  int e = i >> 3, h = i & 7;
  int src = ei[e], dst = ei[E + e];
  float kv[16], qv[16];
  const float4* k4 = (const float4*)(kb + (size_t)src * D + h * HDIM);
  const float4* q4 = (const float4*)(qb + (size_t)dst * D + h * HDIM);
#pragma unroll
  for (int j = 0; j < 4; ++j) {
    float4 a = k4[j]; kv[4 * j] = a.x; kv[4 * j + 1] = a.y; kv[4 * j + 2] = a.z; kv[4 * j + 3] = a.w;
    float4 b = q4[j]; qv[4 * j] = b.x; qv[4 * j + 1] = b.y; qv[4 * j + 2] = b.z; qv[4 * j + 3] = b.w;
  }
  const float* wh = &ws[h * 257];
  float a = 0.f;
#pragma unroll
  for (int d = 0; d < 16; ++d) {
    float t = 0.f;
#pragma unroll
    for (int f = 0; f < 16; ++f) t += wh[d * 16 + f] * qv[f];
    a += kv[d] * t;
  }
  a *= prel_t[h] * 0.25f;  // / sqrt(16)
  att[i] = a;
  atomicMax(&m[dst * 8 + h], enc_f(a));
}

__global__ void k_hgt_pB(const int* __restrict__ e0, const int* __restrict__ e1,
                         const int* __restrict__ e2, const int* __restrict__ e3, int E,
                         float* __restrict__ att, const unsigned* __restrict__ m,
                         float* __restrict__ s) {
  int i = blockIdx.x * 256 + threadIdx.x;
  if (i >= 4 * E * NHEAD) return;
  int per = E * NHEAD;
  int t = i / per, r = i - t * per;
  int e = r >> 3, h = r & 7;
  const int* ei = t == 0 ? e0 : t == 1 ? e1 : t == 2 ? e2 : e3;
  int dst = ei[E + e];
  float mv = dec_f(m[dst * 8 + h]);
  if (!(mv > -3.0e38f)) mv = 0.f;
  float p = expf(att[i] - mv);
  att[i] = p;
  atomicAdd(&s[dst * 8 + h], p);
}

__global__ __launch_bounds__(256) void k_hgt_pC(const int* __restrict__ ei, int E,
                                                const float* __restrict__ vb,
                                                const float* __restrict__ rel,
                                                const float* __restrict__ att,
                                                const float* __restrict__ s,
                                                float* __restrict__ agg) {
  __shared__ float ws[8 * 257];  // mrel[t]
  for (int i = threadIdx.x; i < 2048; i += 256) ws[(i >> 8) * 257 + (i & 255)] = rel[i];
  __syncthreads();
  int i = blockIdx.x * 256 + threadIdx.x;
  if (i >= E * NHEAD) return;
  int e = i >> 3, h = i & 7;
  int src = ei[e], dst = ei[E + e];
  float sv = s[dst * 8 + h];
  float w = att[i] / (sv > 0.f ? sv : 1.f);
  float vv[16];
  const float4* v4 = (const float4*)(vb + (size_t)src * D + h * HDIM);
#pragma unroll
  for (int j = 0; j < 4; ++j) {
    float4 a = v4[j]; vv[4 * j] = a.x; vv[4 * j + 1] = a.y; vv[4 * j + 2] = a.z; vv[4 * j + 3] = a.w;
  }
  const float* wh = &ws[h * 257];
  float* o = agg + (size_t)dst * D + h * HDIM;
#pragma unroll
  for (int f = 0; f < 16; ++f) {
    float t = 0.f;
#pragma unroll
    for (int d = 0; d < 16; ++d) t += vv[d] * wh[d * 16 + f];
    atomicAdd(o + f, t * w);
  }
}

// ---------------- host-side layer driver ----------------
static void gat_layer(const float* Wt, const float* as_, const float* ad_, const float* bias,
                      const float* g, float* h, float* acc, float* xw, float* al, float* ar,
                      unsigned* menc, float* s, const int* const* eis, int N, int E,
                      hipStream_t stream) {
  int nd = N * D;
  k_init_acc_bias<<<(nd + 255) / 256, 256, 0, stream>>>(bias, acc, nd);
  int tot = (E + N) * NHEAD;
  for (int t = 0; t < 4; ++t) {
    k_gemm128<false, false><<<(N + 63) / 64, 256, 0, stream>>>(h, Wt + t * D * D, nullptr, xw, N);
    k_alar<<<(N * NHEAD + 255) / 256, 256, 0, stream>>>(xw, as_ + t * D, ad_ + t * D, al, ar, N);
    k_init_ms<<<(N * NHEAD + 255) / 256, 256, 0, stream>>>(menc, s, N * NHEAD);
    k_gat_p1<<<(tot + 255) / 256, 256, 0, stream>>>(eis[t], E, N, al, ar, menc);
    k_gat_p2<<<(tot + 255) / 256, 256, 0, stream>>>(eis[t], E, N, al, ar, menc, s);
    k_gat_p3<<<(tot + 255) / 256, 256, 0, stream>>>(eis[t], E, N, al, ar, menc, s, xw, acc);
  }
  k_norm<false><<<(N + 3) / 4, 256, 0, stream>>>(h, acc, g, nullptr, h, N);
}

extern "C" void kernel_launch(void* const* d_in, const int* in_sizes, int n_in, void* d_out,
                              int out_size, void* d_ws, size_t ws_size, hipStream_t stream) {
  const float* zL = (const float*)d_in[0];
  const float* zH = (const float*)d_in[1];
  const float* xe = (const float*)d_in[2];
  const float* W1 = (const float*)d_in[3];
  const float* as1 = (const float*)d_in[4];
  const float* ad1 = (const float*)d_in[5];
  const float* b1 = (const float*)d_in[6];
  const float* W2 = (const float*)d_in[7];
  const float* as2 = (const float*)d_in[8];
  const float* ad2 = (const float*)d_in[9];
  const float* b2 = (const float*)d_in[10];
  const float* Wk = (const float*)d_in[11];
  const float* bk = (const float*)d_in[12];
  const float* Wq = (const float*)d_in[13];
  const float* bq = (const float*)d_in[14];
  const float* Wv = (const float*)d_in[15];
  const float* bv = (const float*)d_in[16];
  const float* arel = (const float*)d_in[17];
  const float* mrel = (const float*)d_in[18];
  const float* prel = (const float*)d_in[19];
  const float* Wo = (const float*)d_in[20];
  const float* bo = (const float*)d_in[21];
  const float* skip = (const float*)d_in[22];
  const float* g1 = (const float*)d_in[23];
  const float* g2 = (const float*)d_in[24];
  const float* g3 = (const float*)d_in[25];
  const int* ei[4] = {(const int*)d_in[26], (const int*)d_in[27], (const int*)d_in[28],
                      (const int*)d_in[29]};

  const int N = in_sizes[0] / D;      // 50000
  const int E = in_sizes[26] / 2;     // 150000
  const size_t ND_ = (size_t)N * D;

  // h lives in d_out (rewritten in-place at the end); scratch in d_ws (~102 MB)
  float* h = (float*)d_out;
  float* ws = (float*)d_ws;
  size_t o = 0;
  float* acc = ws + o; o += ND_;                 // GAT out accumulator / HGT agg
  float* xw  = ws + o; o += ND_;                 // per-type x@W / HGT k then v
  float* qb  = ws + o; o += ND_;                 // HGT q / out2
  float* att = ws + o; o += (size_t)4 * E * NHEAD;
  float* al  = ws + o; o += (size_t)N * NHEAD;
  float* ar  = ws + o; o += (size_t)N * NHEAD;
  unsigned* menc = (unsigned*)(ws + o); o += (size_t)N * NHEAD;
  float* s   = ws + o; o += (size_t)N * NHEAD;
  (void)ws_size; (void)n_in; (void)out_size;

  int nd = (int)ND_;
  k_init_h<<<(nd + 255) / 256, 256, 0, stream>>>(zL, zH, xe, h, nd);

  gat_layer(W1, as1, ad1, b1, g1, h, acc, xw, al, ar, menc, s, ei, N, E, stream);
  gat_layer(W2, as2, ad2, b2, g2, h, acc, xw, al, ar, menc, s, ei, N, E, stream);

  // ---- HGT ----
  float* kb = xw;
  k_gemm128<false, true><<<(N + 63) / 64, 256, 0, stream>>>(h, Wk, bk, kb, N);
  k_gemm128<false, true><<<(N + 63) / 64, 256, 0, stream>>>(h, Wq, bq, qb, N);
  k_init_ms<<<(N * NHEAD + 255) / 256, 256, 0, stream>>>(menc, s, N * NHEAD);
  for (int t = 0; t < 4; ++t)
    k_hgt_pA<<<(E * NHEAD + 255) / 256, 256, 0, stream>>>(ei[t], E, kb, qb, arel + t * 2048,
                                                          prel + t * 8, att + (size_t)t * E * NHEAD,
                                                          menc);
  k_hgt_pB<<<(4 * E * NHEAD + 255) / 256, 256, 0, stream>>>(ei[0], ei[1], ei[2], ei[3], E, att,
                                                            menc, s);
  float* vb = xw;  // overwrite k with v (k no longer needed)
  k_gemm128<false, true><<<(N + 63) / 64, 256, 0, stream>>>(h, Wv, bv, vb, N);
  float* agg = acc;
  k_zero<<<(nd + 255) / 256, 256, 0, stream>>>(agg, nd);
  for (int t = 0; t < 4; ++t)
    k_hgt_pC<<<(E * NHEAD + 255) / 256, 256, 0, stream>>>(ei[t], E, vb, mrel + t * 2048,
                                                          att + (size_t)t * E * NHEAD, s, agg);
  // out2 = gelu(agg) @ Wo + bo -> qb
  k_gemm128<true, true><<<(N + 63) / 64, 256, 0, stream>>>(agg, Wo, bo, qb, N);
  // final: d_out = gelu(h + g3 * rmsnorm(beta*out2 + (1-beta)*h))
  k_norm<true><<<(N + 3) / 4, 256, 0, stream>>>(h, qb, g3, skip, (float*)d_out, N);
}

// Round 2
// 2063.862 us; speedup vs baseline: 8.1066x; 8.1066x over previous
//
#include <hip/hip_runtime.h>
#include <math.h>

static constexpr int D = 128;
static constexpr int NHEAD = 8;
static constexpr int HDIM = 16;

__device__ __forceinline__ float gelu_f(float x) {
  return 0.5f * x * (1.0f + erff(x * 0.7071067811865476f));
}
__device__ __forceinline__ float lrelu_f(float x) { return x >= 0.f ? x : 0.2f * x; }

// ---------------- elementwise / init ----------------
__global__ void k_init_h(const float* __restrict__ a, const float* __restrict__ b,
                         const float* __restrict__ c, float* __restrict__ h, int n) {
  int i = blockIdx.x * 256 + threadIdx.x;
  if (i < n) h[i] = a[i] + b[i] + c[i];
}

__global__ void k_init_acc_bias(const float* __restrict__ bias, float* __restrict__ acc, int nd) {
  int i = blockIdx.x * 256 + threadIdx.x;
  if (i < nd) {
    int d = i & (D - 1);
    acc[i] = bias[d] + bias[D + d] + bias[2 * D + d] + bias[3 * D + d];
  }
}

__global__ void k_zero(float* __restrict__ p, int n) {
  int i = blockIdx.x * 256 + threadIdx.x;
  if (i < n) p[i] = 0.f;
}

__global__ void k_zero_i(int* __restrict__ p, int n) {
  int i = blockIdx.x * 256 + threadIdx.x;
  if (i < n) p[i] = 0;
}

__global__ void k_copy_i(const int* __restrict__ a, int* __restrict__ b, int n) {
  int i = blockIdx.x * 256 + threadIdx.x;
  if (i < n) b[i] = a[i];
}

// ---------------- CSR build ----------------
// degAll layout: [0..4N) per-type degrees, [4N..5N) combined degree
__global__ void k_deg(const int* __restrict__ e0, const int* __restrict__ e1,
                      const int* __restrict__ e2, const int* __restrict__ e3, int E, int N,
                      int* __restrict__ degAll) {
  int i = blockIdx.x * 256 + threadIdx.x;
  if (i >= 4 * E) return;
  int t = i / E, e = i - t * E;
  const int* ei = t == 0 ? e0 : t == 1 ? e1 : t == 2 ? e2 : e3;
  int dst = ei[E + e];
  atomicAdd(&degAll[t * N + dst], 1);
  atomicAdd(&degAll[4 * N + dst], 1);
}

// batched exclusive scan over 5 arrays of length N (chunks of 1024)
__global__ __launch_bounds__(256) void k_scan1(const int* __restrict__ degAll,
                                               int* __restrict__ rowAll, int* __restrict__ bsum,
                                               int N, int nblk) {
  int a = blockIdx.y, b = blockIdx.x, tid = threadIdx.x;
  const int* in = degAll + (size_t)a * N;
  int* out = rowAll + (size_t)a * N;
  int idx0 = b * 1024 + tid * 4;
  int v[4], sum = 0;
#pragma unroll
  for (int j = 0; j < 4; ++j) {
    int ix = idx0 + j;
    v[j] = (ix < N) ? in[ix] : 0;
    sum += v[j];
  }
  __shared__ int sh[256];
  sh[tid] = sum;
  __syncthreads();
  for (int off = 1; off < 256; off <<= 1) {
    int t = 0;
    if (tid >= off) t = sh[tid - off];
    __syncthreads();
    sh[tid] += t;
    __syncthreads();
  }
  if (tid == 255) bsum[a * nblk + b] = sh[255];
  int run = (tid > 0) ? sh[tid - 1] : 0;
#pragma unroll
  for (int j = 0; j < 4; ++j) {
    int ix = idx0 + j;
    if (ix < N) out[ix] = run;
    run += v[j];
  }
}

__global__ void k_scan2(int* __restrict__ bsum, int nblk) {
  int a = threadIdx.x;
  if (a >= 5) return;
  int run = 0;
  for (int b = 0; b < nblk; ++b) {
    int t = bsum[a * nblk + b];
    bsum[a * nblk + b] = run;
    run += t;
  }
}

__global__ void k_scan3(int* __restrict__ rowAll, const int* __restrict__ bsum, int N, int nblk) {
  int a = blockIdx.y, b = blockIdx.x;
  int add = bsum[a * nblk + b];
  int* out = rowAll + (size_t)a * N;
  int idx0 = b * 1024 + threadIdx.x * 4;
#pragma unroll
  for (int j = 0; j < 4; ++j) {
    int ix = idx0 + j;
    if (ix < N) out[ix] += add;
  }
}

__global__ void k_fill(const int* __restrict__ e0, const int* __restrict__ e1,
                       const int* __restrict__ e2, const int* __restrict__ e3, int E, int N,
                       int* __restrict__ nextAll, int* __restrict__ srcsT,
                       int* __restrict__ eslotT, int* __restrict__ slotC) {
  int i = blockIdx.x * 256 + threadIdx.x;
  if (i >= 4 * E) return;
  int t = i / E, e = i - t * E;
  const int* ei = t == 0 ? e0 : t == 1 ? e1 : t == 2 ? e2 : e3;
  int src = ei[e], dst = ei[E + e];
  int p = atomicAdd(&nextAll[t * N + dst], 1);
  srcsT[(size_t)t * E + p] = src;
  eslotT[(size_t)t * E + p] = e;
  int pc = atomicAdd(&nextAll[4 * N + dst], 1);
  slotC[pc] = t * E + e;
}

// ---------------- GEMM: C[N,128] = op(A)[N,128] @ W[128,128] (+bias) ----------------
template <bool GELU_A, bool BIAS>
__global__ __launch_bounds__(256) void k_gemm128(const float* __restrict__ A,
                                                 const float* __restrict__ W,
                                                 const float* __restrict__ bias,
                                                 float* __restrict__ C, int N) {
  __shared__ float Ws[D * D];
  __shared__ float As[64 * 132];
  const int tid = threadIdx.x;
  const int row0 = blockIdx.x * 64;
  const int nrows = N - row0;

  const float4* W4 = (const float4*)W;
  float4* Ws4 = (float4*)Ws;
#pragma unroll
  for (int i = 0; i < 16; ++i) Ws4[tid + 256 * i] = W4[tid + 256 * i];

  for (int i = tid; i < 64 * 32; i += 256) {
    int r = i >> 5, c = i & 31;
    float4 v = make_float4(0.f, 0.f, 0.f, 0.f);
    if (r < nrows) v = ((const float4*)A)[(size_t)(row0 + r) * 32 + c];
    if (GELU_A) { v.x = gelu_f(v.x); v.y = gelu_f(v.y); v.z = gelu_f(v.z); v.w = gelu_f(v.w); }
    float* dp = &As[r * 132 + c * 4];
    dp[0] = v.x; dp[1] = v.y; dp[2] = v.z; dp[3] = v.w;
  }
  __syncthreads();

  const int cg = tid & 15, rg = tid >> 4;
  const int c0 = cg * 8, r0 = rg * 4;
  float acc[4][8];
#pragma unroll
  for (int j = 0; j < 4; ++j)
#pragma unroll
    for (int c = 0; c < 8; ++c) acc[j][c] = 0.f;

#pragma unroll 4
  for (int k = 0; k < D; ++k) {
    float4 b0 = *(const float4*)&Ws[k * D + c0];
    float4 b1 = *(const float4*)&Ws[k * D + c0 + 4];
    float a_[4];
#pragma unroll
    for (int j = 0; j < 4; ++j) a_[j] = As[(r0 + j) * 132 + k];
#pragma unroll
    for (int j = 0; j < 4; ++j) {
      acc[j][0] += a_[j] * b0.x; acc[j][1] += a_[j] * b0.y;
      acc[j][2] += a_[j] * b0.z; acc[j][3] += a_[j] * b0.w;
      acc[j][4] += a_[j] * b1.x; acc[j][5] += a_[j] * b1.y;
      acc[j][6] += a_[j] * b1.z; acc[j][7] += a_[j] * b1.w;
    }
  }

#pragma unroll
  for (int j = 0; j < 4; ++j) {
    int r = r0 + j;
    if (r < nrows) {
      float o[8];
#pragma unroll
      for (int c = 0; c < 8; ++c) o[c] = acc[j][c] + (BIAS ? bias[c0 + c] : 0.f);
      float4* Cp = (float4*)&C[(size_t)(row0 + r) * D + c0];
      Cp[0] = make_float4(o[0], o[1], o[2], o[3]);
      Cp[1] = make_float4(o[4], o[5], o[6], o[7]);
    }
  }
}

// ---------------- GAT ----------------
__global__ void k_alar(const float* __restrict__ xw, const float* __restrict__ as_,
                       const float* __restrict__ ad_, float* __restrict__ al,
                       float* __restrict__ ar, int N) {
  int i = blockIdx.x * 256 + threadIdx.x;
  if (i >= N * NHEAD) return;
  int n = i >> 3, h = i & 7;
  const float4* x4 = (const float4*)(xw + (size_t)n * D + h * HDIM);
  const float4* s4 = (const float4*)(as_ + h * HDIM);
  const float4* d4 = (const float4*)(ad_ + h * HDIM);
  float sa = 0.f, sd = 0.f;
#pragma unroll
  for (int j = 0; j < 4; ++j) {
    float4 x = x4[j], s = s4[j], d = d4[j];
    sa += x.x * s.x + x.y * s.y + x.z * s.z + x.w * s.w;
    sd += x.x * d.x + x.y * d.y + x.z * d.z + x.w * d.w;
  }
  al[i] = sa; ar[i] = sd;
}

// gather-based GAT aggregation: 128 threads per dst node, 2 nodes/block.
// acc[n,:] += (p_self*xw[n] + sum_e p_e*xw[src_e]) / s   (self-loop implicit)
__global__ __launch_bounds__(256) void k_gat_agg(const int* __restrict__ rowptr,
                                                 const int* __restrict__ deg,
                                                 const int* __restrict__ srcs,
                                                 const float* __restrict__ al,
                                                 const float* __restrict__ ar,
                                                 const float* __restrict__ xw,
                                                 float* __restrict__ acc, int N) {
  int n = blockIdx.x * 2 + (threadIdx.x >> 7);
  if (n >= N) return;
  int h = (threadIdx.x >> 4) & 7, f = threadIdx.x & 15;
  int rs = rowptr[n], dg = deg[n];
  float arn = ar[n * 8 + h];
  float lself = lrelu_f(al[n * 8 + h] + arn);
  float m = lself;
  for (int i = 0; i < dg; ++i) {
    int src = srcs[rs + i];
    m = fmaxf(m, lrelu_f(al[src * 8 + h] + arn));
  }
  float p = __expf(lself - m);
  float s = p;
  float accf = p * xw[(size_t)n * D + h * HDIM + f];
  for (int i = 0; i < dg; ++i) {
    int src = srcs[rs + i];
    float pe = __expf(lrelu_f(al[src * 8 + h] + arn) - m);
    s += pe;
    accf += pe * xw[(size_t)src * D + h * HDIM + f];
  }
  acc[(size_t)n * D + h * HDIM + f] += accf / s;
}

// ---------------- fused residual + RMSNorm + GELU ----------------
template <bool MIX>
__global__ __launch_bounds__(256) void k_norm(const float* __restrict__ hin,
                                              const float* __restrict__ o_,
                                              const float* __restrict__ g,
                                              const float* __restrict__ skip,
                                              float* __restrict__ hout, int N) {
  int w = threadIdx.x >> 6, lane = threadIdx.x & 63;
  int row = blockIdx.x * 4 + w;
  if (row >= N) return;
  size_t base = (size_t)row * D;
  float h0 = hin[base + lane], h1 = hin[base + 64 + lane];
  float o0 = o_[base + lane], o1 = o_[base + 64 + lane];
  if (MIX) {
    float beta = 1.f / (1.f + expf(-skip[0]));
    o0 = beta * o0 + (1.f - beta) * h0;
    o1 = beta * o1 + (1.f - beta) * h1;
  }
  float ss = o0 * o0 + o1 * o1;
#pragma unroll
  for (int msk = 1; msk < 64; msk <<= 1) ss += __shfl_xor(ss, msk, 64);
  float r = rsqrtf(ss * (1.f / 128.f) + 1e-6f);
  float y0 = h0 + g[lane] * o0 * r;
  float y1 = h1 + g[64 + lane] * o1 * r;
  hout[base + lane] = gelu_f(y0);
  hout[base + 64 + lane] = gelu_f(y1);
}

// ---------------- HGT ----------------
// A: per-edge logits (no atomics), thread per (edge, head)
__global__ __launch_bounds__(256) void k_hgt_pA(const int* __restrict__ ei, int E,
                                                const float* __restrict__ kb,
                                                const float* __restrict__ qb,
                                                const float* __restrict__ rel,
                                                const float* __restrict__ prel_t,
                                                float* __restrict__ att) {
  __shared__ float ws[8 * 257];
  for (int i = threadIdx.x; i < 2048; i += 256) ws[(i >> 8) * 257 + (i & 255)] = rel[i];
  __syncthreads();
  int i = blockIdx.x * 256 + threadIdx.x;
  if (i >= E * NHEAD) return;
  int e = i >> 3, h = i & 7;
  int src = ei[e], dst = ei[E + e];
  float kv[16], qv[16];
  const float4* k4 = (const float4*)(kb + (size_t)src * D + h * HDIM);
  const float4* q4 = (const float4*)(qb + (size_t)dst * D + h * HDIM);
#pragma unroll
  for (int j = 0; j < 4; ++j) {
    float4 a = k4[j]; kv[4 * j] = a.x; kv[4 * j + 1] = a.y; kv[4 * j + 2] = a.z; kv[4 * j + 3] = a.w;
    float4 b = q4[j]; qv[4 * j] = b.x; qv[4 * j + 1] = b.y; qv[4 * j + 2] = b.z; qv[4 * j + 3] = b.w;
  }
  const float* wh = &ws[h * 257];
  float a = 0.f;
#pragma unroll
  for (int d = 0; d < 16; ++d) {
    float t = 0.f;
#pragma unroll
    for (int f = 0; f < 16; ++f) t += wh[d * 16 + f] * qv[f];
    a += kv[d] * t;
  }
  att[i] = a * prel_t[h] * 0.25f;
}

// B: joint softmax over combined CSR; att <- exp(att - m), s[n,h] = sum
__global__ void k_hgt_B(const int* __restrict__ rowptrC, const int* __restrict__ degC,
                        const int* __restrict__ slotC, float* __restrict__ att,
                        float* __restrict__ s, int N) {
  int i = blockIdx.x * 256 + threadIdx.x;
  if (i >= N * NHEAD) return;
  int n = i >> 3, h = i & 7;
  int rs = rowptrC[n], dg = degC[n];
  if (dg == 0) { s[i] = 0.f; return; }
  float m = -3.4e38f;
  for (int j = 0; j < dg; ++j) m = fmaxf(m, att[(size_t)slotC[rs + j] * 8 + h]);
  float ss = 0.f;
  for (int j = 0; j < dg; ++j) {
    size_t ix = (size_t)slotC[rs + j] * 8 + h;
    float p = __expf(att[ix] - m);
    ss += p;
    att[ix] = p;
  }
  s[i] = ss;
}

// C: per-type gather-aggregate with in-register mrel matvec (16-lane shfl broadcast)
__global__ __launch_bounds__(256) void k_hgt_C(const int* __restrict__ rowptr,
                                               const int* __restrict__ deg,
                                               const int* __restrict__ srcs,
                                               const int* __restrict__ eslot,
                                               const float* __restrict__ vb,
                                               const float* __restrict__ rel,
                                               const float* __restrict__ att_t,
                                               const float* __restrict__ s,
                                               float* __restrict__ acc, int N) {
  __shared__ float ws[8 * 257];
  for (int i = threadIdx.x; i < 2048; i += 256) ws[(i >> 8) * 257 + (i & 255)] = rel[i];
  __syncthreads();
  int n = blockIdx.x * 2 + (threadIdx.x >> 7);
  if (n >= N) return;
  int h = (threadIdx.x >> 4) & 7, f = threadIdx.x & 15;
  int lane = threadIdx.x & 63;
  int gb = lane & 48;
  int rs = rowptr[n], dg = deg[n];
  if (dg == 0) return;
  float sv = s[n * 8 + h];
  float inv = sv > 0.f ? 1.f / sv : 1.f;
  const float* wh = &ws[h * 257];
  float accf = 0.f;
  for (int i = 0; i < dg; ++i) {
    int src = srcs[rs + i];
    int e = eslot[rs + i];
    float w = att_t[(size_t)e * 8 + h] * inv;
    float vf = vb[(size_t)src * D + h * HDIM + f];
    float msg = 0.f;
#pragma unroll
    for (int d = 0; d < 16; ++d) {
      float vd = __shfl(vf, gb + d, 64);
      msg += vd * wh[d * 16 + f];
    }
    accf += w * msg;
  }
  acc[(size_t)n * D + h * HDIM + f] += accf;
}

// ---------------- host-side ----------------
static void gat_layer(const float* Wt, const float* as_, const float* ad_, const float* bias,
                      const float* g, float* h, float* acc, float* xw, float* al, float* ar,
                      const int* rowAll, const int* degAll, const int* srcsT, int N, int E,
                      hipStream_t stream) {
  int nd = N * D;
  k_init_acc_bias<<<(nd + 255) / 256, 256, 0, stream>>>(bias, acc, nd);
  for (int t = 0; t < 4; ++t) {
    k_gemm128<false, false><<<(N + 63) / 64, 256, 0, stream>>>(h, Wt + t * D * D, nullptr, xw, N);
    k_alar<<<(N * NHEAD + 255) / 256, 256, 0, stream>>>(xw, as_ + t * D, ad_ + t * D, al, ar, N);
    k_gat_agg<<<(N + 1) / 2, 256, 0, stream>>>(rowAll + (size_t)t * N, degAll + (size_t)t * N,
                                               srcsT + (size_t)t * E, al, ar, xw, acc, N);
  }
  k_norm<false><<<(N + 3) / 4, 256, 0, stream>>>(h, acc, g, nullptr, h, N);
}

extern "C" void kernel_launch(void* const* d_in, const int* in_sizes, int n_in, void* d_out,
                              int out_size, void* d_ws, size_t ws_size, hipStream_t stream) {
  const float* zL = (const float*)d_in[0];
  const float* zH = (const float*)d_in[1];
  const float* xe = (const float*)d_in[2];
  const float* W1 = (const float*)d_in[3];
  const float* as1 = (const float*)d_in[4];
  const float* ad1 = (const float*)d_in[5];
  const float* b1 = (const float*)d_in[6];
  const float* W2 = (const float*)d_in[7];
  const float* as2 = (const float*)d_in[8];
  const float* ad2 = (const float*)d_in[9];
  const float* b2 = (const float*)d_in[10];
  const float* Wk = (const float*)d_in[11];
  const float* bk = (const float*)d_in[12];
  const float* Wq = (const float*)d_in[13];
  const float* bq = (const float*)d_in[14];
  const float* Wv = (const float*)d_in[15];
  const float* bv = (const float*)d_in[16];
  const float* arel = (const float*)d_in[17];
  const float* mrel = (const float*)d_in[18];
  const float* prel = (const float*)d_in[19];
  const float* Wo = (const float*)d_in[20];
  const float* bo = (const float*)d_in[21];
  const float* skip = (const float*)d_in[22];
  const float* g1 = (const float*)d_in[23];
  const float* g2 = (const float*)d_in[24];
  const float* g3 = (const float*)d_in[25];
  const int* ei[4] = {(const int*)d_in[26], (const int*)d_in[27], (const int*)d_in[28],
                      (const int*)d_in[29]};

  const int N = in_sizes[0] / D;   // 50000
  const int E = in_sizes[26] / 2;  // 150000
  const size_t ND_ = (size_t)N * D;
  (void)ws_size; (void)n_in; (void)out_size;

  float* h = (float*)d_out;
  float* ws = (float*)d_ws;
  size_t o = 0;
  float* acc = ws + o; o += ND_;
  float* xw  = ws + o; o += ND_;   // GAT xw; HGT k then v
  float* qb  = ws + o; o += ND_;   // HGT q; then out2
  float* att = ws + o; o += (size_t)4 * E * NHEAD;
  float* al  = ws + o; o += (size_t)N * NHEAD;
  float* ar  = ws + o; o += (size_t)N * NHEAD;
  float* sden = ws + o; o += (size_t)N * NHEAD;
  int* ib = (int*)(ws + o);
  size_t io = 0;
  int* degAll  = ib + io; io += 5 * (size_t)N;
  int* rowAll  = ib + io; io += 5 * (size_t)N;
  int* nextAll = ib + io; io += 5 * (size_t)N;
  int* bsum    = ib + io; io += 5 * 64;
  int* srcsT   = ib + io; io += 4 * (size_t)E;
  int* eslotT  = ib + io; io += 4 * (size_t)E;
  int* slotC   = ib + io; io += 4 * (size_t)E;

  const int nd = (int)ND_;
  const int nblk = (N + 1023) / 1024;

  k_init_h<<<(nd + 255) / 256, 256, 0, stream>>>(zL, zH, xe, h, nd);

  // ---- CSR build (reused by both GAT layers and HGT) ----
  k_zero_i<<<(5 * N + 255) / 256, 256, 0, stream>>>(degAll, 5 * N);
  k_deg<<<(4 * E + 255) / 256, 256, 0, stream>>>(ei[0], ei[1], ei[2], ei[3], E, N, degAll);
  k_scan1<<<dim3(nblk, 5), 256, 0, stream>>>(degAll, rowAll, bsum, N, nblk);
  k_scan2<<<1, 64, 0, stream>>>(bsum, nblk);
  k_scan3<<<dim3(nblk, 5), 256, 0, stream>>>(rowAll, bsum, N, nblk);
  k_copy_i<<<(5 * N + 255) / 256, 256, 0, stream>>>(rowAll, nextAll, 5 * N);
  k_fill<<<(4 * E + 255) / 256, 256, 0, stream>>>(ei[0], ei[1], ei[2], ei[3], E, N, nextAll,
                                                  srcsT, eslotT, slotC);

  // ---- GAT layers ----
  gat_layer(W1, as1, ad1, b1, g1, h, acc, xw, al, ar, rowAll, degAll, srcsT, N, E, stream);
  gat_layer(W2, as2, ad2, b2, g2, h, acc, xw, al, ar, rowAll, degAll, srcsT, N, E, stream);

  // ---- HGT ----
  float* kb = xw;
  k_gemm128<false, true><<<(N + 63) / 64, 256, 0, stream>>>(h, Wk, bk, kb, N);
  k_gemm128<false, true><<<(N + 63) / 64, 256, 0, stream>>>(h, Wq, bq, qb, N);
  for (int t = 0; t < 4; ++t)
    k_hgt_pA<<<(E * NHEAD + 255) / 256, 256, 0, stream>>>(
        ei[t], E, kb, qb, arel + t * 2048, prel + t * 8, att + (size_t)t * E * NHEAD);
  k_hgt_B<<<(N * NHEAD + 255) / 256, 256, 0, stream>>>(rowAll + 4 * (size_t)N,
                                                       degAll + 4 * (size_t)N, slotC, att, sden, N);
  float* vb = xw;
  k_gemm128<false, true><<<(N + 63) / 64, 256, 0, stream>>>(h, Wv, bv, vb, N);
  k_zero<<<(nd + 255) / 256, 256, 0, stream>>>(acc, nd);
  for (int t = 0; t < 4; ++t)
    k_hgt_C<<<(N + 1) / 2, 256, 0, stream>>>(rowAll + (size_t)t * N, degAll + (size_t)t * N,
                                             srcsT + (size_t)t * E, eslotT + (size_t)t * E, vb,
                                             mrel + t * 2048, att + (size_t)t * E * NHEAD, sden,
                                             acc, N);
  k_gemm128<true, true><<<(N + 63) / 64, 256, 0, stream>>>(acc, Wo, bo, qb, N);
  k_norm<true><<<(N + 3) / 4, 256, 0, stream>>>(h, qb, g3, skip, (float*)d_out, N);
}

// Round 3
// 1701.228 us; speedup vs baseline: 9.8346x; 1.2132x over previous
//
#include <hip/hip_runtime.h>
#include <math.h>

static constexpr int D = 128;
static constexpr int NHEAD = 8;

typedef __attribute__((ext_vector_type(8))) short short8;
typedef __attribute__((ext_vector_type(4))) float f32x4;

__device__ __forceinline__ float gelu_f(float x) {
  return 0.5f * x * (1.0f + erff(x * 0.7071067811865476f));
}
__device__ __forceinline__ float lrelu_f(float x) { return x >= 0.f ? x : 0.2f * x; }
__device__ __forceinline__ unsigned short f2b(float f) {
  unsigned u = __float_as_uint(f);
  return (unsigned short)((u + 0x7fffu + ((u >> 16) & 1u)) >> 16);
}
__device__ __forceinline__ float b2f(unsigned short b) {
  return __uint_as_float((unsigned)b << 16);
}
__device__ __forceinline__ void ldbf16x16(const unsigned short* p, float* o) {
  uint4 a = *(const uint4*)p;
  uint4 b = *(const uint4*)(p + 8);
  unsigned w[8] = {a.x, a.y, a.z, a.w, b.x, b.y, b.z, b.w};
#pragma unroll
  for (int j = 0; j < 8; ++j) {
    o[2 * j] = __uint_as_float(w[j] << 16);
    o[2 * j + 1] = __uint_as_float(w[j] & 0xffff0000u);
  }
}

// ---------------- elementwise / init ----------------
__global__ void k_init_h(const float* __restrict__ a, const float* __restrict__ b,
                         const float* __restrict__ c, float* __restrict__ h, int n) {
  int i = blockIdx.x * 256 + threadIdx.x;
  if (i < n) h[i] = a[i] + b[i] + c[i];
}

__global__ void k_init_acc_bias(const float* __restrict__ bias, float* __restrict__ acc, int nd) {
  int i = blockIdx.x * 256 + threadIdx.x;
  if (i < nd) {
    int d = i & (D - 1);
    acc[i] = bias[d] + bias[D + d] + bias[2 * D + d] + bias[3 * D + d];
  }
}

__global__ void k_zero_i(int* __restrict__ p, int n) {
  int i = blockIdx.x * 256 + threadIdx.x;
  if (i < n) p[i] = 0;
}

__global__ void k_copy_i(const int* __restrict__ a, int* __restrict__ b, int n) {
  int i = blockIdx.x * 256 + threadIdx.x;
  if (i < n) b[i] = a[i];
}

// ---------------- CSR build (combined, sorted by (dst, type)) ----------------
__global__ void k_deg(const int* __restrict__ e0, const int* __restrict__ e1,
                      const int* __restrict__ e2, const int* __restrict__ e3, int E, int N,
                      int* __restrict__ deg2) {
  int i = blockIdx.x * 256 + threadIdx.x;
  if (i >= 4 * E) return;
  int t = i / E, e = i - t * E;
  const int* ei = t == 0 ? e0 : t == 1 ? e1 : t == 2 ? e2 : e3;
  atomicAdd(&deg2[ei[E + e] * 4 + t], 1);
}

__global__ __launch_bounds__(256) void k_scan1(const int* __restrict__ in, int* __restrict__ out,
                                               int* __restrict__ bsum, int n, int nblk) {
  int b = blockIdx.x, tid = threadIdx.x;
  int idx0 = b * 1024 + tid * 4;
  int v[4], sum = 0;
#pragma unroll
  for (int j = 0; j < 4; ++j) {
    int ix = idx0 + j;
    v[j] = (ix < n) ? in[ix] : 0;
    sum += v[j];
  }
  __shared__ int sh[256];
  sh[tid] = sum;
  __syncthreads();
  for (int off = 1; off < 256; off <<= 1) {
    int t = 0;
    if (tid >= off) t = sh[tid - off];
    __syncthreads();
    sh[tid] += t;
    __syncthreads();
  }
  if (tid == 255) bsum[b] = sh[255];
  int run = (tid > 0) ? sh[tid - 1] : 0;
#pragma unroll
  for (int j = 0; j < 4; ++j) {
    int ix = idx0 + j;
    if (ix < n) out[ix] = run;
    run += v[j];
  }
}

__global__ void k_scan2b(int* __restrict__ bsum, int nblk) {
  __shared__ int sh[256];
  int tid = threadIdx.x;
  int v = (tid < nblk) ? bsum[tid] : 0;
  sh[tid] = v;
  __syncthreads();
  for (int off = 1; off < 256; off <<= 1) {
    int t = (tid >= off) ? sh[tid - off] : 0;
    __syncthreads();
    sh[tid] += t;
    __syncthreads();
  }
  if (tid < nblk) bsum[tid] = sh[tid] - v;
}

__global__ void k_scan3(int* __restrict__ out, const int* __restrict__ bsum, int n, int nblk) {
  int b = blockIdx.x;
  int add = bsum[b];
  int idx0 = b * 1024 + threadIdx.x * 4;
#pragma unroll
  for (int j = 0; j < 4; ++j) {
    int ix = idx0 + j;
    if (ix < n) out[ix] += add;
  }
}

__global__ void k_fill(const int* __restrict__ e0, const int* __restrict__ e1,
                       const int* __restrict__ e2, const int* __restrict__ e3, int E, int N,
                       int* __restrict__ next2, int* __restrict__ cs_src,
                       int* __restrict__ eslot2) {
  int i = blockIdx.x * 256 + threadIdx.x;
  if (i >= 4 * E) return;
  int t = i / E, e = i - t * E;
  const int* ei = t == 0 ? e0 : t == 1 ? e1 : t == 2 ? e2 : e3;
  int src = ei[e], dst = ei[E + e];
  int pos = atomicAdd(&next2[dst * 4 + t], 1);
  cs_src[pos] = src;
  eslot2[i] = pos;
}

// ---------------- MFMA GEMM: C[N,*] = op(A)[N,128] @ Wbt^T (+bias) ----------------
// Wbt: [NC][128] bf16 (row = output col). 128x128 tile, 256 thr = 4 waves (2x2 of 64x64).
template <bool GELU_A, bool OUT_BF16>
__global__ __launch_bounds__(256) void k_gemm_mfma(const float* __restrict__ A,
                                                   const unsigned short* __restrict__ Wbt,
                                                   const float* __restrict__ bias0,
                                                   const float* __restrict__ bias1,
                                                   const float* __restrict__ bias2,
                                                   void* __restrict__ Cout, int N, int ldc) {
  __shared__ short8 As[2048];  // [128 rows][16 chunks of 8 bf16], XOR-swizzled
  __shared__ short8 Bs[2048];
  const int tid = threadIdx.x;
  const int row0 = blockIdx.x * 128;
  const int ct128 = blockIdx.y;
  const int col0 = ct128 * 128;

  {  // stage A: f32 -> bf16, swizzled
    int r = tid >> 1, half = tid & 1;
    int grow = row0 + r;
    bool ok = grow < N;
    const float* ap = A + (size_t)grow * 128 + half * 64;
#pragma unroll
    for (int j = 0; j < 8; ++j) {
      short8 pk = {0, 0, 0, 0, 0, 0, 0, 0};
      if (ok) {
        float4 v0 = ((const float4*)ap)[2 * j];
        float4 v1 = ((const float4*)ap)[2 * j + 1];
        float f[8] = {v0.x, v0.y, v0.z, v0.w, v1.x, v1.y, v1.z, v1.w};
#pragma unroll
        for (int q = 0; q < 8; ++q) {
          float x = f[q];
          if (GELU_A) x = gelu_f(x);
          pk[q] = (short)f2b(x);
        }
      }
      int chunk = half * 8 + j;
      As[r * 16 + (chunk ^ (r & 7))] = pk;
    }
  }
  {  // stage B: Wbt rows (bf16) -> LDS, swizzled
    int c = tid >> 1, half = tid & 1;
    const short8* wp = (const short8*)(Wbt + (size_t)(col0 + c) * 128 + half * 64);
#pragma unroll
    for (int j = 0; j < 8; ++j) {
      int chunk = half * 8 + j;
      Bs[c * 16 + (chunk ^ (c & 7))] = wp[j];
    }
  }
  __syncthreads();

  const int w = tid >> 6, lane = tid & 63;
  const int wr = w >> 1, wc = w & 1;
  const int lr = lane & 15, lg = lane >> 4;
  f32x4 acc[4][4];
#pragma unroll
  for (int i = 0; i < 4; ++i)
#pragma unroll
    for (int j = 0; j < 4; ++j) acc[i][j] = f32x4{0.f, 0.f, 0.f, 0.f};

#pragma unroll
  for (int ks = 0; ks < 4; ++ks) {
    short8 af[4], bfr[4];
#pragma unroll
    for (int rt = 0; rt < 4; ++rt) {
      int row = wr * 64 + rt * 16 + lr;
      af[rt] = As[row * 16 + ((ks * 4 + lg) ^ (row & 7))];
    }
#pragma unroll
    for (int ct = 0; ct < 4; ++ct) {
      int cc = wc * 64 + ct * 16 + lr;
      bfr[ct] = Bs[cc * 16 + ((ks * 4 + lg) ^ (cc & 7))];
    }
#pragma unroll
    for (int rt = 0; rt < 4; ++rt)
#pragma unroll
      for (int ct = 0; ct < 4; ++ct)
        acc[rt][ct] =
            __builtin_amdgcn_mfma_f32_16x16x32_bf16(af[rt], bfr[ct], acc[rt][ct], 0, 0, 0);
  }

  const float* bias = ct128 == 0 ? bias0 : (ct128 == 1 ? bias1 : bias2);
#pragma unroll
  for (int rt = 0; rt < 4; ++rt) {
#pragma unroll
    for (int ct = 0; ct < 4; ++ct) {
      int cloc = wc * 64 + ct * 16 + lr;
      int col = col0 + cloc;
      float bv = bias ? bias[cloc] : 0.f;
#pragma unroll
      for (int j = 0; j < 4; ++j) {
        int row = row0 + wr * 64 + rt * 16 + lg * 4 + j;
        if (row < N) {
          float val = acc[rt][ct][j] + bv;
          if (OUT_BF16)
            ((unsigned short*)Cout)[(size_t)row * ldc + col] = f2b(val);
          else
            ((float*)Cout)[(size_t)row * ldc + col] = val;
        }
      }
    }
  }
}

// ---------------- W transpose+convert: Wbt[(t*128+n)][k] = W_t[k][n] ----------------
__global__ void k_cvtW(const float* __restrict__ W0, const float* __restrict__ W1,
                       const float* __restrict__ W2, const float* __restrict__ W3, int ntile,
                       unsigned short* __restrict__ out) {
  int i = blockIdx.x * 256 + threadIdx.x;
  if (i >= ntile * 16384) return;
  int t = i >> 14, r = i & 16383;
  int n = r >> 7, k = r & 127;
  const float* W = t == 0 ? W0 : t == 1 ? W1 : t == 2 ? W2 : W3;
  out[i] = f2b(W[k * 128 + n]);
}

// ---------------- GAT ----------------
__global__ void k_alar(const unsigned short* __restrict__ xwb, const float* __restrict__ as_,
                       const float* __restrict__ ad_, float* __restrict__ al,
                       float* __restrict__ ar, int N) {
  int i = blockIdx.x * 256 + threadIdx.x;
  if (i >= N * NHEAD) return;
  int n = i >> 3, h = i & 7;
  float x[16];
  ldbf16x16(xwb + (size_t)n * D + h * 16, x);
  float sa = 0.f, sd = 0.f;
#pragma unroll
  for (int j = 0; j < 16; ++j) {
    sa += x[j] * as_[h * 16 + j];
    sd += x[j] * ad_[h * 16 + j];
  }
  al[i] = sa;
  ar[i] = sd;
}

__global__ __launch_bounds__(256) void k_gat_agg(const int* __restrict__ base2,
                                                 const int* __restrict__ cs_src,
                                                 const float* __restrict__ al,
                                                 const float* __restrict__ ar,
                                                 const unsigned short* __restrict__ xwb,
                                                 float* __restrict__ acc, int N, int t,
                                                 int fourE) {
  int n = blockIdx.x * 2 + (threadIdx.x >> 7);
  if (n >= N) return;
  int h = (threadIdx.x >> 4) & 7, f = threadIdx.x & 15;
  int idx = n * 4 + t;
  int rs = base2[idx];
  int re = (idx + 1 < 4 * N) ? base2[idx + 1] : fourE;
  float arn = ar[n * 8 + h];
  float lself = lrelu_f(al[n * 8 + h] + arn);
  float m = lself;
  for (int i = rs; i < re; ++i) {
    int src = cs_src[i];
    m = fmaxf(m, lrelu_f(al[src * 8 + h] + arn));
  }
  float p = __expf(lself - m);
  float s = p;
  float accf = p * b2f(xwb[(size_t)n * D + h * 16 + f]);
  for (int i = rs; i < re; ++i) {
    int src = cs_src[i];
    float pe = __expf(lrelu_f(al[src * 8 + h] + arn) - m);
    s += pe;
    accf += pe * b2f(xwb[(size_t)src * D + h * 16 + f]);
  }
  acc[(size_t)n * D + h * 16 + f] += accf / s;
}

// ---------------- fused residual + RMSNorm + GELU ----------------
template <bool MIX>
__global__ __launch_bounds__(256) void k_norm(const float* __restrict__ hin,
                                              const float* __restrict__ o_,
                                              const float* __restrict__ g,
                                              const float* __restrict__ skip,
                                              float* __restrict__ hout, int N) {
  int w = threadIdx.x >> 6, lane = threadIdx.x & 63;
  int row = blockIdx.x * 4 + w;
  if (row >= N) return;
  size_t base = (size_t)row * D;
  float h0 = hin[base + lane], h1 = hin[base + 64 + lane];
  float o0 = o_[base + lane], o1 = o_[base + 64 + lane];
  if (MIX) {
    float beta = 1.f / (1.f + expf(-skip[0]));
    o0 = beta * o0 + (1.f - beta) * h0;
    o1 = beta * o1 + (1.f - beta) * h1;
  }
  float ss = o0 * o0 + o1 * o1;
#pragma unroll
  for (int msk = 1; msk < 64; msk <<= 1) ss += __shfl_xor(ss, msk, 64);
  float r = rsqrtf(ss * (1.f / 128.f) + 1e-6f);
  hout[base + lane] = gelu_f(h0 + g[lane] * o0 * r);
  hout[base + 64 + lane] = gelu_f(h1 + g[64 + lane] * o1 * r);
}

// ---------------- HGT ----------------
// qa[n,h,d] = sum_f arel[h,d,f] * q[n,h,f]
__global__ __launch_bounds__(256) void k_qa(const unsigned short* __restrict__ kqv,
                                            const float* __restrict__ rel, float* __restrict__ qa,
                                            int N) {
  __shared__ float ws[8 * 257];  // [h][f][d] transposed for bank spread
  for (int i = threadIdx.x; i < 2048; i += 256) {
    int h = i >> 8, r = i & 255, d = r >> 4, fq = r & 15;
    ws[h * 257 + fq * 16 + d] = rel[i];
  }
  __syncthreads();
  int i = blockIdx.x * 256 + threadIdx.x;
  if (i >= N * 128) return;
  int n = i >> 7, hd = i & 127, h = hd >> 4, d = hd & 15;
  float qf[16];
  ldbf16x16(kqv + (size_t)n * 384 + 128 + h * 16, qf);
  const float* wh = &ws[h * 257 + d];
  float a = 0.f;
#pragma unroll
  for (int fq = 0; fq < 16; ++fq) a += wh[fq * 16] * qf[fq];
  qa[i] = a;
}

// att[slot,h] = prel/4 * dot16(k[src,h], qa[dst,h])
__global__ void k_logit(const int* __restrict__ ei, int E, const int* __restrict__ eslot2_t,
                        const unsigned short* __restrict__ kqv, const float* __restrict__ qa,
                        const float* __restrict__ prel_t, unsigned short* __restrict__ att) {
  int i = blockIdx.x * 256 + threadIdx.x;
  if (i >= E * NHEAD) return;
  int e = i >> 3, h = i & 7;
  int src = ei[e], dst = ei[E + e];
  int slot = eslot2_t[e];
  float kf[16];
  ldbf16x16(kqv + (size_t)src * 384 + h * 16, kf);
  const float* qp = qa + (size_t)dst * 128 + h * 16;
  float a = 0.f;
#pragma unroll
  for (int j = 0; j < 16; ++j) a += kf[j] * qp[j];
  att[(size_t)slot * 8 + h] = f2b(a * prel_t[h] * 0.25f);
}

// joint softmax per (n,h) over combined contiguous segment
__global__ void k_hgt_B(const int* __restrict__ base2, unsigned short* __restrict__ att,
                        float* __restrict__ sden, int N, int fourE) {
  int i = blockIdx.x * 256 + threadIdx.x;
  if (i >= N * NHEAD) return;
  int n = i >> 3, h = i & 7;
  int rs = base2[n * 4];
  int re = (n == N - 1) ? fourE : base2[n * 4 + 4];
  if (re == rs) { sden[i] = 0.f; return; }
  float m = -3.4e38f;
  for (int j = rs; j < re; ++j) m = fmaxf(m, b2f(att[(size_t)j * 8 + h]));
  float ss = 0.f;
  for (int j = rs; j < re; ++j) {
    float p = __expf(b2f(att[(size_t)j * 8 + h]) - m);
    ss += p;
    att[(size_t)j * 8 + h] = f2b(p);
  }
  sden[i] = ss;
}

// per-node: aggT[d] = sum_e p_e*v[src,h,d]; out[h,f] = (sum_t aggT @ mrel[t,h]) / s
__global__ __launch_bounds__(256) void k_hgt_agg(const int* __restrict__ base2,
                                                 const int* __restrict__ cs_src,
                                                 const unsigned short* __restrict__ att,
                                                 const float* __restrict__ sden,
                                                 const unsigned short* __restrict__ kqv,
                                                 const float* __restrict__ mrel4,
                                                 float* __restrict__ acc, int N, int fourE) {
  __shared__ float mw[4 * 2056];
  for (int i = threadIdx.x; i < 8192; i += 256) {
    int t = i >> 11, r = i & 2047;
    mw[t * 2056 + (r >> 8) * 257 + (r & 255)] = mrel4[i];
  }
  __syncthreads();
  int n = blockIdx.x * 2 + (threadIdx.x >> 7);
  if (n >= N) return;
  int h = (threadIdx.x >> 4) & 7, f = threadIdx.x & 15;
  int gb = (threadIdx.x & 63) & 48;
  float sv = sden[n * 8 + h];
  float inv = sv > 0.f ? 1.f / sv : 0.f;
  float out = 0.f;
  for (int t = 0; t < 4; ++t) {
    int idx = n * 4 + t;
    int rs = base2[idx];
    int re = (idx + 1 < 4 * N) ? base2[idx + 1] : fourE;
    float aggd = 0.f;
    for (int i = rs; i < re; ++i) {
      float wgt = b2f(att[(size_t)i * 8 + h]);
      int src = cs_src[i];
      aggd += wgt * b2f(kqv[(size_t)src * 384 + 256 + h * 16 + f]);
    }
    const float* wh = &mw[t * 2056 + h * 257];
#pragma unroll
    for (int d = 0; d < 16; ++d) {
      float vd = __shfl(aggd, gb + d, 64);
      out += vd * wh[d * 16 + f];
    }
  }
  acc[(size_t)n * D + h * 16 + f] = out * inv;
}

// ---------------- host side ----------------
static void gat_layer(const float* Wt, const float* as_, const float* ad_, const float* bias,
                      const float* g, float* h, float* acc, unsigned short* xwb,
                      unsigned short* Wbt, float* al, float* ar, const int* base2,
                      const int* cs_src, int N, int fourE, hipStream_t stream) {
  int nd = N * D;
  int nb128 = (N + 127) / 128;
  k_cvtW<<<(4 * 16384 + 255) / 256, 256, 0, stream>>>(Wt, Wt + 16384, Wt + 32768, Wt + 49152, 4,
                                                      Wbt);
  k_init_acc_bias<<<(nd + 255) / 256, 256, 0, stream>>>(bias, acc, nd);
  for (int t = 0; t < 4; ++t) {
    k_gemm_mfma<false, true><<<dim3(nb128, 1), 256, 0, stream>>>(
        h, Wbt + (size_t)t * 16384, nullptr, nullptr, nullptr, xwb, N, 128);
    k_alar<<<(N * NHEAD + 255) / 256, 256, 0, stream>>>(xwb, as_ + t * D, ad_ + t * D, al, ar, N);
    k_gat_agg<<<(N + 1) / 2, 256, 0, stream>>>(base2, cs_src, al, ar, xwb, acc, N, t, fourE);
  }
  k_norm<false><<<(N + 3) / 4, 256, 0, stream>>>(h, acc, g, nullptr, h, N);
}

extern "C" void kernel_launch(void* const* d_in, const int* in_sizes, int n_in, void* d_out,
                              int out_size, void* d_ws, size_t ws_size, hipStream_t stream) {
  const float* zL = (const float*)d_in[0];
  const float* zH = (const float*)d_in[1];
  const float* xe = (const float*)d_in[2];
  const float* W1 = (const float*)d_in[3];
  const float* as1 = (const float*)d_in[4];
  const float* ad1 = (const float*)d_in[5];
  const float* b1 = (const float*)d_in[6];
  const float* W2 = (const float*)d_in[7];
  const float* as2 = (const float*)d_in[8];
  const float* ad2 = (const float*)d_in[9];
  const float* b2 = (const float*)d_in[10];
  const float* Wk = (const float*)d_in[11];
  const float* bk = (const float*)d_in[12];
  const float* Wq = (const float*)d_in[13];
  const float* bq = (const float*)d_in[14];
  const float* Wv = (const float*)d_in[15];
  const float* bv = (const float*)d_in[16];
  const float* arel = (const float*)d_in[17];
  const float* mrel = (const float*)d_in[18];
  const float* prel = (const float*)d_in[19];
  const float* Wo = (const float*)d_in[20];
  const float* bo = (const float*)d_in[21];
  const float* skip = (const float*)d_in[22];
  const float* g1 = (const float*)d_in[23];
  const float* g2 = (const float*)d_in[24];
  const float* g3 = (const float*)d_in[25];
  const int* ei[4] = {(const int*)d_in[26], (const int*)d_in[27], (const int*)d_in[28],
                      (const int*)d_in[29]};

  const int N = in_sizes[0] / D;   // 50000
  const int E = in_sizes[26] / 2;  // 150000
  const int fourE = 4 * E;
  const int fourN = 4 * N;
  const size_t ND_ = (size_t)N * D;
  (void)ws_size; (void)n_in; (void)out_size;

  float* h = (float*)d_out;
  float* ws = (float*)d_ws;
  size_t o = 0;
  float* acc = ws + o; o += ND_;                           // GAT acc / HGT qa / HGT agg-out
  float* bigf = ws + o;                                    // out2 overlay (f32 N*128)
  unsigned short* bigb = (unsigned short*)bigf;            // xwb / kqv bf16
  o += (size_t)N * 384 / 2;                                // N*384 ushorts
  unsigned short* attb = (unsigned short*)(ws + o); o += (size_t)fourE * 8 / 2;
  float* al = ws + o; o += (size_t)N * NHEAD;
  float* ar = ws + o; o += (size_t)N * NHEAD;
  float* sden = ws + o; o += (size_t)N * NHEAD;
  unsigned short* Wbt = (unsigned short*)(ws + o); o += 512 * 128 / 2;
  int* ib = (int*)(ws + o);
  size_t io = 0;
  int* deg2 = ib + io; io += fourN;
  int* base2 = ib + io; io += fourN;
  int* next2 = ib + io; io += fourN;
  int* bsum = ib + io; io += 256;
  int* cs_src = ib + io; io += fourE;
  int* eslot2 = ib + io; io += fourE;

  const int nd = (int)ND_;
  const int nb128 = (N + 127) / 128;
  const int nblk4 = (fourN + 1023) / 1024;

  k_init_h<<<(nd + 255) / 256, 256, 0, stream>>>(zL, zH, xe, h, nd);

  // ---- CSR (combined, (dst,type)-sorted; reused by all layers) ----
  k_zero_i<<<(fourN + 255) / 256, 256, 0, stream>>>(deg2, fourN);
  k_deg<<<(fourE + 255) / 256, 256, 0, stream>>>(ei[0], ei[1], ei[2], ei[3], E, N, deg2);
  k_scan1<<<nblk4, 256, 0, stream>>>(deg2, base2, bsum, fourN, nblk4);
  k_scan2b<<<1, 256, 0, stream>>>(bsum, nblk4);
  k_scan3<<<nblk4, 256, 0, stream>>>(base2, bsum, fourN, nblk4);
  k_copy_i<<<(fourN + 255) / 256, 256, 0, stream>>>(base2, next2, fourN);
  k_fill<<<(fourE + 255) / 256, 256, 0, stream>>>(ei[0], ei[1], ei[2], ei[3], E, N, next2, cs_src,
                                                  eslot2);

  // ---- GAT layers ----
  gat_layer(W1, as1, ad1, b1, g1, h, acc, bigb, Wbt, al, ar, base2, cs_src, N, fourE, stream);
  gat_layer(W2, as2, ad2, b2, g2, h, acc, bigb, Wbt, al, ar, base2, cs_src, N, fourE, stream);

  // ---- HGT ----
  unsigned short* kqvb = bigb;  // [N][384] bf16: k|q|v
  k_cvtW<<<(3 * 16384 + 255) / 256, 256, 0, stream>>>(Wk, Wq, Wv, Wv, 3, Wbt);
  k_gemm_mfma<false, true><<<dim3(nb128, 3), 256, 0, stream>>>(h, Wbt, bk, bq, bv, kqvb, N, 384);
  float* qa = acc;
  for (int t = 0; t < 4; ++t) {
    k_qa<<<(N * 128 + 255) / 256, 256, 0, stream>>>(kqvb, arel + t * 2048, qa, N);
    k_logit<<<(E * NHEAD + 255) / 256, 256, 0, stream>>>(ei[t], E, eslot2 + (size_t)t * E, kqvb,
                                                         qa, prel + t * 8, attb);
  }
  k_hgt_B<<<(N * NHEAD + 255) / 256, 256, 0, stream>>>(base2, attb, sden, N, fourE);
  k_hgt_agg<<<(N + 1) / 2, 256, 0, stream>>>(base2, cs_src, attb, sden, kqvb, mrel, acc, N, fourE);
  // out2 = gelu(acc) @ Wo + bo   (overlays the kqv region, which is dead now)
  float* out2 = bigf;
  k_cvtW<<<(16384 + 255) / 256, 256, 0, stream>>>(Wo, Wo, Wo, Wo, 1, Wbt);
  k_gemm_mfma<true, false><<<dim3(nb128, 1), 256, 0, stream>>>(acc, Wbt, bo, nullptr, nullptr,
                                                               out2, N, 128);
  k_norm<true><<<(N + 3) / 4, 256, 0, stream>>>(h, out2, g3, skip, (float*)d_out, N);
}

// Round 4
// 1397.379 us; speedup vs baseline: 11.9730x; 1.2174x over previous
//
#include <hip/hip_runtime.h>
#include <math.h>

static constexpr int D = 128;
static constexpr int NHEAD = 8;

typedef __attribute__((ext_vector_type(8))) short short8;
typedef __attribute__((ext_vector_type(4))) float f32x4;

__device__ __forceinline__ float gelu_f(float x) {
  return 0.5f * x * (1.0f + erff(x * 0.7071067811865476f));
}
__device__ __forceinline__ float lrelu_f(float x) { return x >= 0.f ? x : 0.2f * x; }
__device__ __forceinline__ unsigned short f2b(float f) {
  unsigned u = __float_as_uint(f);
  return (unsigned short)((u + 0x7fffu + ((u >> 16) & 1u)) >> 16);
}
__device__ __forceinline__ float b2f(unsigned short b) {
  return __uint_as_float((unsigned)b << 16);
}
__device__ __forceinline__ void ldbf16x16(const unsigned short* p, float* o) {
  uint4 a = *(const uint4*)p;
  uint4 b = *(const uint4*)(p + 8);
  unsigned w[8] = {a.x, a.y, a.z, a.w, b.x, b.y, b.z, b.w};
#pragma unroll
  for (int j = 0; j < 8; ++j) {
    o[2 * j] = __uint_as_float(w[j] << 16);
    o[2 * j + 1] = __uint_as_float(w[j] & 0xffff0000u);
  }
}

// ---------------- elementwise / init ----------------
__global__ void k_init_h(const float* __restrict__ a, const float* __restrict__ b,
                         const float* __restrict__ c, float* __restrict__ h, int n) {
  int i = blockIdx.x * 256 + threadIdx.x;
  if (i < n) h[i] = a[i] + b[i] + c[i];
}

__global__ void k_init_acc_bias(const float* __restrict__ bias, float* __restrict__ acc, int nd) {
  int i = blockIdx.x * 256 + threadIdx.x;
  if (i < nd) {
    int d = i & (D - 1);
    acc[i] = bias[d] + bias[D + d] + bias[2 * D + d] + bias[3 * D + d];
  }
}

__global__ void k_zero_i(int* __restrict__ p, int n) {
  int i = blockIdx.x * 256 + threadIdx.x;
  if (i < n) p[i] = 0;
}

__global__ void k_copy_i(const int* __restrict__ a, int* __restrict__ b, int n) {
  int i = blockIdx.x * 256 + threadIdx.x;
  if (i < n) b[i] = a[i];
}

// ---------------- CSR build (combined, sorted by (dst, type)) ----------------
__global__ void k_deg(const int* __restrict__ e0, const int* __restrict__ e1,
                      const int* __restrict__ e2, const int* __restrict__ e3, int E, int N,
                      int* __restrict__ deg2) {
  int i = blockIdx.x * 256 + threadIdx.x;
  if (i >= 4 * E) return;
  int t = i / E, e = i - t * E;
  const int* ei = t == 0 ? e0 : t == 1 ? e1 : t == 2 ? e2 : e3;
  atomicAdd(&deg2[ei[E + e] * 4 + t], 1);
}

__global__ __launch_bounds__(256) void k_scan1(const int* __restrict__ in, int* __restrict__ out,
                                               int* __restrict__ bsum, int n, int nblk) {
  int b = blockIdx.x, tid = threadIdx.x;
  int idx0 = b * 1024 + tid * 4;
  int v[4], sum = 0;
#pragma unroll
  for (int j = 0; j < 4; ++j) {
    int ix = idx0 + j;
    v[j] = (ix < n) ? in[ix] : 0;
    sum += v[j];
  }
  __shared__ int sh[256];
  sh[tid] = sum;
  __syncthreads();
  for (int off = 1; off < 256; off <<= 1) {
    int t = 0;
    if (tid >= off) t = sh[tid - off];
    __syncthreads();
    sh[tid] += t;
    __syncthreads();
  }
  if (tid == 255) bsum[b] = sh[255];
  int run = (tid > 0) ? sh[tid - 1] : 0;
#pragma unroll
  for (int j = 0; j < 4; ++j) {
    int ix = idx0 + j;
    if (ix < n) out[ix] = run;
    run += v[j];
  }
}

__global__ void k_scan2b(int* __restrict__ bsum, int nblk) {
  __shared__ int sh[256];
  int tid = threadIdx.x;
  int v = (tid < nblk) ? bsum[tid] : 0;
  sh[tid] = v;
  __syncthreads();
  for (int off = 1; off < 256; off <<= 1) {
    int t = (tid >= off) ? sh[tid - off] : 0;
    __syncthreads();
    sh[tid] += t;
    __syncthreads();
  }
  if (tid < nblk) bsum[tid] = sh[tid] - v;
}

__global__ void k_scan3(int* __restrict__ out, const int* __restrict__ bsum, int n, int nblk) {
  int b = blockIdx.x;
  int add = bsum[b];
  int idx0 = b * 1024 + threadIdx.x * 4;
#pragma unroll
  for (int j = 0; j < 4; ++j) {
    int ix = idx0 + j;
    if (ix < n) out[ix] += add;
  }
}

__global__ void k_fill(const int* __restrict__ e0, const int* __restrict__ e1,
                       const int* __restrict__ e2, const int* __restrict__ e3, int E, int N,
                       int* __restrict__ next2, int* __restrict__ cs_src,
                       int* __restrict__ eslot2) {
  int i = blockIdx.x * 256 + threadIdx.x;
  if (i >= 4 * E) return;
  int t = i / E, e = i - t * E;
  const int* ei = t == 0 ? e0 : t == 1 ? e1 : t == 2 ? e2 : e3;
  int src = ei[e], dst = ei[E + e];
  int pos = atomicAdd(&next2[dst * 4 + t], 1);
  cs_src[pos] = src;
  eslot2[i] = pos;
}

// ---------------- MFMA GEMM: C[N,*] (+)= op(A)[N,128] @ Wbt^T (+bias) ----------------
// Wbt: [NC][128] bf16 (row = output col). 128x128 tile, 256 thr = 4 waves (2x2 of 64x64).
// AMODE: 0 = f32 A, 1 = f32 A + gelu, 2 = bf16 A.
template <int AMODE, bool OUT_BF16, bool ACCUM>
__global__ __launch_bounds__(256) void k_gemm_mfma(const void* __restrict__ Ain, int lda,
                                                   const unsigned short* __restrict__ Wbt,
                                                   const float* __restrict__ bias0,
                                                   const float* __restrict__ bias1,
                                                   const float* __restrict__ bias2,
                                                   void* __restrict__ Cout, int N, int ldc) {
  __shared__ short8 As[2048];  // [128 rows][16 chunks of 8 bf16], XOR-swizzled
  __shared__ short8 Bs[2048];
  const int tid = threadIdx.x;
  const int row0 = blockIdx.x * 128;
  const int ct128 = blockIdx.y;
  const int col0 = ct128 * 128;

  {  // stage A
    int r = tid >> 1, half = tid & 1;
    int grow = row0 + r;
    bool ok = grow < N;
    if (AMODE == 2) {
      const unsigned short* ap = (const unsigned short*)Ain + (size_t)grow * lda + half * 64;
#pragma unroll
      for (int j = 0; j < 8; ++j) {
        short8 pk = {0, 0, 0, 0, 0, 0, 0, 0};
        if (ok) pk = ((const short8*)ap)[j];
        int chunk = half * 8 + j;
        As[r * 16 + (chunk ^ (r & 7))] = pk;
      }
    } else {
      const float* ap = (const float*)Ain + (size_t)grow * lda + half * 64;
#pragma unroll
      for (int j = 0; j < 8; ++j) {
        short8 pk = {0, 0, 0, 0, 0, 0, 0, 0};
        if (ok) {
          float4 v0 = ((const float4*)ap)[2 * j];
          float4 v1 = ((const float4*)ap)[2 * j + 1];
          float f[8] = {v0.x, v0.y, v0.z, v0.w, v1.x, v1.y, v1.z, v1.w};
#pragma unroll
          for (int q = 0; q < 8; ++q) {
            float x = f[q];
            if (AMODE == 1) x = gelu_f(x);
            pk[q] = (short)f2b(x);
          }
        }
        int chunk = half * 8 + j;
        As[r * 16 + (chunk ^ (r & 7))] = pk;
      }
    }
  }
  {  // stage B
    int c = tid >> 1, half = tid & 1;
    const short8* wp = (const short8*)(Wbt + (size_t)(col0 + c) * 128 + half * 64);
#pragma unroll
    for (int j = 0; j < 8; ++j) {
      int chunk = half * 8 + j;
      Bs[c * 16 + (chunk ^ (c & 7))] = wp[j];
    }
  }
  __syncthreads();

  const int w = tid >> 6, lane = tid & 63;
  const int wr = w >> 1, wc = w & 1;
  const int lr = lane & 15, lg = lane >> 4;
  f32x4 acc[4][4];
#pragma unroll
  for (int i = 0; i < 4; ++i)
#pragma unroll
    for (int j = 0; j < 4; ++j) acc[i][j] = f32x4{0.f, 0.f, 0.f, 0.f};

#pragma unroll
  for (int ks = 0; ks < 4; ++ks) {
    short8 af[4], bfr[4];
#pragma unroll
    for (int rt = 0; rt < 4; ++rt) {
      int row = wr * 64 + rt * 16 + lr;
      af[rt] = As[row * 16 + ((ks * 4 + lg) ^ (row & 7))];
    }
#pragma unroll
    for (int ct = 0; ct < 4; ++ct) {
      int cc = wc * 64 + ct * 16 + lr;
      bfr[ct] = Bs[cc * 16 + ((ks * 4 + lg) ^ (cc & 7))];
    }
#pragma unroll
    for (int rt = 0; rt < 4; ++rt)
#pragma unroll
      for (int ct = 0; ct < 4; ++ct)
        acc[rt][ct] =
            __builtin_amdgcn_mfma_f32_16x16x32_bf16(af[rt], bfr[ct], acc[rt][ct], 0, 0, 0);
  }

  const float* bias = ct128 == 0 ? bias0 : (ct128 == 1 ? bias1 : bias2);
#pragma unroll
  for (int rt = 0; rt < 4; ++rt) {
#pragma unroll
    for (int ct = 0; ct < 4; ++ct) {
      int cloc = wc * 64 + ct * 16 + lr;
      int col = col0 + cloc;
      float bv = bias ? bias[cloc] : 0.f;
#pragma unroll
      for (int j = 0; j < 4; ++j) {
        int row = row0 + wr * 64 + rt * 16 + lg * 4 + j;
        if (row < N) {
          float val = acc[rt][ct][j] + bv;
          if (OUT_BF16) {
            ((unsigned short*)Cout)[(size_t)row * ldc + col] = f2b(val);
          } else {
            float* cp = (float*)Cout + (size_t)row * ldc + col;
            if (ACCUM) val += *cp;
            *cp = val;
          }
        }
      }
    }
  }
}

// ---------------- W transpose+convert: Wbt[(t*128+n)][k] = W_t[k][n] ----------------
__global__ void k_cvtW(const float* __restrict__ W0, const float* __restrict__ W1,
                       const float* __restrict__ W2, const float* __restrict__ W3, int ntile,
                       unsigned short* __restrict__ out) {
  int i = blockIdx.x * 256 + threadIdx.x;
  if (i >= ntile * 16384) return;
  int t = i >> 14, r = i & 16383;
  int n = r >> 7, k = r & 127;
  const float* W = t == 0 ? W0 : t == 1 ? W1 : t == 2 ? W2 : W3;
  out[i] = f2b(W[k * 128 + n]);
}

// block-diagonal mrel in Wbt format: Wbd[t][col=h*16+f][k=h*16+d] = mrel[t,h,d,f]
__global__ void k_cvt_mbd(const float* __restrict__ mrel4, unsigned short* __restrict__ Wbd) {
  int i = blockIdx.x * 256 + threadIdx.x;
  if (i >= 4 * 16384) return;
  int t = i >> 14, r = i & 16383;
  int col = r >> 7, k = r & 127;
  int hc = col >> 4, fq = col & 15, hk = k >> 4, d = k & 15;
  float v = (hc == hk) ? mrel4[t * 2048 + hc * 256 + d * 16 + fq] : 0.f;
  Wbd[i] = f2b(v);
}

// ---------------- GAT ----------------
__global__ void k_alar(const unsigned short* __restrict__ xwb, const float* __restrict__ as_,
                       const float* __restrict__ ad_, float* __restrict__ al,
                       float* __restrict__ ar, int N) {
  int i = blockIdx.x * 256 + threadIdx.x;
  if (i >= N * NHEAD) return;
  int n = i >> 3, h = i & 7;
  float x[16];
  ldbf16x16(xwb + (size_t)n * D + h * 16, x);
  float sa = 0.f, sd = 0.f;
#pragma unroll
  for (int j = 0; j < 16; ++j) {
    sa += x[j] * as_[h * 16 + j];
    sd += x[j] * ad_[h * 16 + j];
  }
  al[i] = sa;
  ar[i] = sd;
}

// single-pass online-softmax gather aggregation, batch-4 prefetched edge loop
__global__ __launch_bounds__(256) void k_gat_agg(const int* __restrict__ base2,
                                                 const int* __restrict__ cs_src,
                                                 const float* __restrict__ al,
                                                 const float* __restrict__ ar,
                                                 const unsigned short* __restrict__ xwb,
                                                 float* __restrict__ acc, int N, int t,
                                                 int fourE) {
  int n = blockIdx.x * 2 + (threadIdx.x >> 7);
  if (n >= N) return;
  int h = (threadIdx.x >> 4) & 7, f = threadIdx.x & 15;
  int idx = n * 4 + t;
  int rs = base2[idx];
  int re = (idx + 1 < 4 * N) ? base2[idx + 1] : fourE;
  float arn = ar[n * 8 + h];
  float xs = lrelu_f(al[n * 8 + h] + arn);  // self-loop
  float m = xs, s = 1.f;
  float accf = b2f(xwb[(size_t)n * D + h * 16 + f]);
  for (int i = rs; i < re; i += 4) {
    int cnt = re - i;
    int sj[4];
    float aj[4], vj[4];
#pragma unroll
    for (int j = 0; j < 4; ++j) sj[j] = (j < cnt) ? cs_src[i + j] : 0;
#pragma unroll
    for (int j = 0; j < 4; ++j) aj[j] = al[sj[j] * 8 + h];
#pragma unroll
    for (int j = 0; j < 4; ++j) vj[j] = b2f(xwb[(size_t)sj[j] * D + h * 16 + f]);
#pragma unroll
    for (int j = 0; j < 4; ++j) {
      float x = (j < cnt) ? lrelu_f(aj[j] + arn) : -3.0e38f;
      float mn = fmaxf(m, x);
      float r = __expf(m - mn);
      float p = __expf(x - mn);
      s = s * r + p;
      accf = accf * r + p * vj[j];
      m = mn;
    }
  }
  acc[(size_t)n * D + h * 16 + f] += accf / s;
}

// ---------------- fused residual + RMSNorm + GELU ----------------
template <bool MIX>
__global__ __launch_bounds__(256) void k_norm(const float* __restrict__ hin,
                                              const float* __restrict__ o_,
                                              const float* __restrict__ g,
                                              const float* __restrict__ skip,
                                              float* __restrict__ hout, int N) {
  int w = threadIdx.x >> 6, lane = threadIdx.x & 63;
  int row = blockIdx.x * 4 + w;
  if (row >= N) return;
  size_t base = (size_t)row * D;
  float h0 = hin[base + lane], h1 = hin[base + 64 + lane];
  float o0 = o_[base + lane], o1 = o_[base + 64 + lane];
  if (MIX) {
    float beta = 1.f / (1.f + expf(-skip[0]));
    o0 = beta * o0 + (1.f - beta) * h0;
    o1 = beta * o1 + (1.f - beta) * h1;
  }
  float ss = o0 * o0 + o1 * o1;
#pragma unroll
  for (int msk = 1; msk < 64; msk <<= 1) ss += __shfl_xor(ss, msk, 64);
  float r = rsqrtf(ss * (1.f / 128.f) + 1e-6f);
  hout[base + lane] = gelu_f(h0 + g[lane] * o0 * r);
  hout[base + 64 + lane] = gelu_f(h1 + g[64 + lane] * o1 * r);
}

// ---------------- HGT ----------------
// qa[n,h,d] = sum_f arel[h,d,f] * q[n,h,f]  (bf16 out)
__global__ __launch_bounds__(256) void k_qa(const unsigned short* __restrict__ kqv,
                                            const float* __restrict__ rel,
                                            unsigned short* __restrict__ qab, int N) {
  __shared__ float ws[8 * 257];  // [h][f][d] transposed
  for (int i = threadIdx.x; i < 2048; i += 256) {
    int h = i >> 8, r = i & 255, d = r >> 4, fq = r & 15;
    ws[h * 257 + fq * 16 + d] = rel[i];
  }
  __syncthreads();
  int i = blockIdx.x * 256 + threadIdx.x;
  if (i >= N * 128) return;
  int n = i >> 7, hd = i & 127, h = hd >> 4, d = hd & 15;
  float qf[16];
  ldbf16x16(kqv + (size_t)n * 384 + 128 + h * 16, qf);
  const float* wh = &ws[h * 257 + d];
  float a = 0.f;
#pragma unroll
  for (int fq = 0; fq < 16; ++fq) a += wh[fq * 16] * qf[fq];
  qab[i] = f2b(a);
}

// att[slot,h] = prel/4 * dot16(k[src,h], qa[dst,h])   (raw logits, bf16)
__global__ void k_logit(const int* __restrict__ ei, int E, const int* __restrict__ eslot2_t,
                        const unsigned short* __restrict__ kqv,
                        const unsigned short* __restrict__ qab, const float* __restrict__ prel_t,
                        unsigned short* __restrict__ att) {
  int i = blockIdx.x * 256 + threadIdx.x;
  if (i >= E * NHEAD) return;
  int e = i >> 3, h = i & 7;
  int src = ei[e], dst = ei[E + e];
  int slot = eslot2_t[e];
  float kf[16], qf[16];
  ldbf16x16(kqv + (size_t)src * 384 + h * 16, kf);
  ldbf16x16(qab + (size_t)dst * 128 + h * 16, qf);
  float a = 0.f;
#pragma unroll
  for (int j = 0; j < 16; ++j) a += kf[j] * qf[j];
  att[(size_t)slot * 8 + h] = f2b(a * prel_t[h] * 0.25f);
}

// joint-softmax reduction only: per (n,h) online max & sum over combined segment
__global__ void k_hgt_Bred(const int* __restrict__ base2, const unsigned short* __restrict__ att,
                           float* __restrict__ mden, float* __restrict__ sinv, int N, int fourE) {
  int i = blockIdx.x * 256 + threadIdx.x;
  if (i >= N * NHEAD) return;
  int n = i >> 3, h = i & 7;
  int rs = base2[n * 4];
  int re = (n == N - 1) ? fourE : base2[n * 4 + 4];
  if (re == rs) {
    mden[i] = 0.f;
    sinv[i] = 0.f;
    return;
  }
  float m = -3.0e38f, s = 0.f;
  for (int j = rs; j < re; j += 8) {
    int cnt = re - j;
    float a[8];
#pragma unroll
    for (int q = 0; q < 8; ++q)
      a[q] = (q < cnt) ? b2f(att[(size_t)(j + q) * 8 + h]) : -3.0e38f;
#pragma unroll
    for (int q = 0; q < 8; ++q) {
      float mn = fmaxf(m, a[q]);
      s = s * __expf(m - mn) + __expf(a[q] - mn);
      m = mn;
    }
  }
  mden[i] = m;
  sinv[i] = 1.f / s;
}

// per-type weighted v gather-sum (no mrel here): aggT[n,h*16+f] = inv * sum_e exp(a-m)*v[src]
__global__ __launch_bounds__(256) void k_hgt_agg2(const int* __restrict__ base2,
                                                  const int* __restrict__ cs_src,
                                                  const unsigned short* __restrict__ att,
                                                  const float* __restrict__ mden,
                                                  const float* __restrict__ sinv,
                                                  const unsigned short* __restrict__ kqv,
                                                  unsigned short* __restrict__ aggT, int N, int t,
                                                  int fourE) {
  int n = blockIdx.x * 2 + (threadIdx.x >> 7);
  if (n >= N) return;
  int h = (threadIdx.x >> 4) & 7, f = threadIdx.x & 15;
  int idx = n * 4 + t;
  int rs = base2[idx];
  int re = (idx + 1 < 4 * N) ? base2[idx + 1] : fourE;
  float m = mden[n * 8 + h], inv = sinv[n * 8 + h];
  float aggf = 0.f;
  for (int i = rs; i < re; i += 4) {
    int cnt = re - i;
    int sj[4];
    float aj[4], vj[4];
#pragma unroll
    for (int j = 0; j < 4; ++j) sj[j] = (j < cnt) ? cs_src[i + j] : 0;
#pragma unroll
    for (int j = 0; j < 4; ++j) aj[j] = (j < cnt) ? b2f(att[(size_t)(i + j) * 8 + h]) : 0.f;
#pragma unroll
    for (int j = 0; j < 4; ++j) vj[j] = b2f(kqv[(size_t)sj[j] * 384 + 256 + h * 16 + f]);
#pragma unroll
    for (int j = 0; j < 4; ++j) {
      float w = (j < cnt) ? __expf(aj[j] - m) : 0.f;
      aggf += w * vj[j];
    }
  }
  aggT[(size_t)n * 128 + h * 16 + f] = f2b(aggf * inv);
}

// ---------------- host side ----------------
static void gat_layer(const float* Wt, const float* as_, const float* ad_, const float* bias,
                      const float* g, float* h, float* acc, unsigned short* xwb,
                      unsigned short* Wbt, float* al, float* ar, const int* base2,
                      const int* cs_src, int N, int fourE, hipStream_t stream) {
  int nd = N * D;
  int nb128 = (N + 127) / 128;
  k_cvtW<<<(4 * 16384 + 255) / 256, 256, 0, stream>>>(Wt, Wt + 16384, Wt + 32768, Wt + 49152, 4,
                                                      Wbt);
  k_init_acc_bias<<<(nd + 255) / 256, 256, 0, stream>>>(bias, acc, nd);
  for (int t = 0; t < 4; ++t) {
    k_gemm_mfma<0, true, false><<<dim3(nb128, 1), 256, 0, stream>>>(
        h, 128, Wbt + (size_t)t * 16384, nullptr, nullptr, nullptr, xwb, N, 128);
    k_alar<<<(N * NHEAD + 255) / 256, 256, 0, stream>>>(xwb, as_ + t * D, ad_ + t * D, al, ar, N);
    k_gat_agg<<<(N + 1) / 2, 256, 0, stream>>>(base2, cs_src, al, ar, xwb, acc, N, t, fourE);
  }
  k_norm<false><<<(N + 3) / 4, 256, 0, stream>>>(h, acc, g, nullptr, h, N);
}

extern "C" void kernel_launch(void* const* d_in, const int* in_sizes, int n_in, void* d_out,
                              int out_size, void* d_ws, size_t ws_size, hipStream_t stream) {
  const float* zL = (const float*)d_in[0];
  const float* zH = (const float*)d_in[1];
  const float* xe = (const float*)d_in[2];
  const float* W1 = (const float*)d_in[3];
  const float* as1 = (const float*)d_in[4];
  const float* ad1 = (const float*)d_in[5];
  const float* b1 = (const float*)d_in[6];
  const float* W2 = (const float*)d_in[7];
  const float* as2 = (const float*)d_in[8];
  const float* ad2 = (const float*)d_in[9];
  const float* b2 = (const float*)d_in[10];
  const float* Wk = (const float*)d_in[11];
  const float* bk = (const float*)d_in[12];
  const float* Wq = (const float*)d_in[13];
  const float* bq = (const float*)d_in[14];
  const float* Wv = (const float*)d_in[15];
  const float* bv = (const float*)d_in[16];
  const float* arel = (const float*)d_in[17];
  const float* mrel = (const float*)d_in[18];
  const float* prel = (const float*)d_in[19];
  const float* Wo = (const float*)d_in[20];
  const float* bo = (const float*)d_in[21];
  const float* skip = (const float*)d_in[22];
  const float* g1 = (const float*)d_in[23];
  const float* g2 = (const float*)d_in[24];
  const float* g3 = (const float*)d_in[25];
  const int* ei[4] = {(const int*)d_in[26], (const int*)d_in[27], (const int*)d_in[28],
                      (const int*)d_in[29]};

  const int N = in_sizes[0] / D;   // 50000
  const int E = in_sizes[26] / 2;  // 150000
  const int fourE = 4 * E;
  const int fourN = 4 * N;
  const size_t ND_ = (size_t)N * D;
  (void)ws_size;
  (void)n_in;
  (void)out_size;

  float* h = (float*)d_out;
  float* ws = (float*)d_ws;
  size_t o = 0;
  float* acc = ws + o; o += ND_;                 // GAT acc / HGT qa(bf16 overlay) / chain C
  unsigned short* reg2 = (unsigned short*)(ws + o); o += (size_t)N * 192;  // xw (GAT) / kqv / out2
  unsigned short* attb = (unsigned short*)(ws + o); o += (size_t)fourE * 4;
  float* al = ws + o; o += (size_t)N * NHEAD;    // HGT: mden
  float* ar = ws + o; o += (size_t)N * NHEAD;    // HGT: sinv
  unsigned short* aggT = (unsigned short*)(ws + o); o += (size_t)N * 64;  // [N][128] bf16
  unsigned short* Wbt = (unsigned short*)(ws + o); o += 512 * 128 / 2;
  unsigned short* Wbd = (unsigned short*)(ws + o); o += 4 * 16384 / 2;
  int* ib = (int*)(ws + o);
  size_t io = 0;
  int* deg2 = ib + io; io += fourN;
  int* base2 = ib + io; io += fourN;
  int* next2 = ib + io; io += fourN;
  int* bsum = ib + io; io += 256;
  int* cs_src = ib + io; io += fourE;
  int* eslot2 = ib + io; io += fourE;

  const int nd = (int)ND_;
  const int nb128 = (N + 127) / 128;
  const int nblk4 = (fourN + 1023) / 1024;

  k_init_h<<<(nd + 255) / 256, 256, 0, stream>>>(zL, zH, xe, h, nd);

  // ---- CSR (combined, (dst,type)-sorted; reused by all layers) ----
  k_zero_i<<<(fourN + 255) / 256, 256, 0, stream>>>(deg2, fourN);
  k_deg<<<(fourE + 255) / 256, 256, 0, stream>>>(ei[0], ei[1], ei[2], ei[3], E, N, deg2);
  k_scan1<<<nblk4, 256, 0, stream>>>(deg2, base2, bsum, fourN, nblk4);
  k_scan2b<<<1, 256, 0, stream>>>(bsum, nblk4);
  k_scan3<<<nblk4, 256, 0, stream>>>(base2, bsum, fourN, nblk4);
  k_copy_i<<<(fourN + 255) / 256, 256, 0, stream>>>(base2, next2, fourN);
  k_fill<<<(fourE + 255) / 256, 256, 0, stream>>>(ei[0], ei[1], ei[2], ei[3], E, N, next2, cs_src,
                                                  eslot2);

  // ---- GAT layers ----
  gat_layer(W1, as1, ad1, b1, g1, h, acc, reg2, Wbt, al, ar, base2, cs_src, N, fourE, stream);
  gat_layer(W2, as2, ad2, b2, g2, h, acc, reg2, Wbt, al, ar, base2, cs_src, N, fourE, stream);

  // ---- HGT ----
  unsigned short* kqvb = reg2;  // [N][384] bf16: k|q|v
  k_cvtW<<<(3 * 16384 + 255) / 256, 256, 0, stream>>>(Wk, Wq, Wv, Wv, 3, Wbt);
  k_gemm_mfma<0, true, false><<<dim3(nb128, 3), 256, 0, stream>>>(h, 128, Wbt, bk, bq, bv, kqvb,
                                                                  N, 384);
  k_cvt_mbd<<<(4 * 16384 + 255) / 256, 256, 0, stream>>>(mrel, Wbd);
  unsigned short* qab = (unsigned short*)acc;  // qa overlay (dead before chain GEMMs write acc)
  for (int t = 0; t < 4; ++t) {
    k_qa<<<(N * 128 + 255) / 256, 256, 0, stream>>>(kqvb, arel + t * 2048, qab, N);
    k_logit<<<(E * NHEAD + 255) / 256, 256, 0, stream>>>(ei[t], E, eslot2 + (size_t)t * E, kqvb,
                                                         qab, prel + t * 8, attb);
  }
  float* mden = al;
  float* sinv = ar;
  k_hgt_Bred<<<(N * NHEAD + 255) / 256, 256, 0, stream>>>(base2, attb, mden, sinv, N, fourE);
  for (int t = 0; t < 4; ++t) {
    k_hgt_agg2<<<(N + 1) / 2, 256, 0, stream>>>(base2, cs_src, attb, mden, sinv, kqvb, aggT, N, t,
                                                fourE);
    if (t == 0)
      k_gemm_mfma<2, false, false><<<dim3(nb128, 1), 256, 0, stream>>>(
          aggT, 128, Wbd + (size_t)t * 16384, nullptr, nullptr, nullptr, acc, N, 128);
    else
      k_gemm_mfma<2, false, true><<<dim3(nb128, 1), 256, 0, stream>>>(
          aggT, 128, Wbd + (size_t)t * 16384, nullptr, nullptr, nullptr, acc, N, 128);
  }
  // out2 = gelu(acc) @ Wo + bo   (overlays kqv region, dead now)
  float* out2 = (float*)reg2;
  k_cvtW<<<(16384 + 255) / 256, 256, 0, stream>>>(Wo, Wo, Wo, Wo, 1, Wbt);
  k_gemm_mfma<1, false, false><<<dim3(nb128, 1), 256, 0, stream>>>(acc, 128, Wbt, bo, nullptr,
                                                                   nullptr, out2, N, 128);
  k_norm<true><<<(N + 3) / 4, 256, 0, stream>>>(h, out2, g3, skip, (float*)d_out, N);
}

// Round 6
// 1009.947 us; speedup vs baseline: 16.5661x; 1.3836x over previous
//
#include <hip/hip_runtime.h>
#include <math.h>

static constexpr int D = 128;

typedef __attribute__((ext_vector_type(8))) short short8;
typedef __attribute__((ext_vector_type(4))) float f32x4;

__device__ __forceinline__ float gelu_f(float x) {
  return 0.5f * x * (1.0f + erff(x * 0.7071067811865476f));
}
__device__ __forceinline__ float lrelu_f(float x) { return x >= 0.f ? x : 0.2f * x; }
__device__ __forceinline__ unsigned short f2b(float f) {
  unsigned u = __float_as_uint(f);
  return (unsigned short)((u + 0x7fffu + ((u >> 16) & 1u)) >> 16);
}
__device__ __forceinline__ float b2f(unsigned short b) {
  return __uint_as_float((unsigned)b << 16);
}
__device__ __forceinline__ void ldbf16x16(const unsigned short* p, float* o) {
  uint4 a = *(const uint4*)p;
  uint4 b = *(const uint4*)(p + 8);
  unsigned w[8] = {a.x, a.y, a.z, a.w, b.x, b.y, b.z, b.w};
#pragma unroll
  for (int j = 0; j < 8; ++j) {
    o[2 * j] = __uint_as_float(w[j] << 16);
    o[2 * j + 1] = __uint_as_float(w[j] & 0xffff0000u);
  }
}

// ---------------- elementwise / init ----------------
__global__ void k_init_h(const float* __restrict__ a, const float* __restrict__ b,
                         const float* __restrict__ c, float* __restrict__ h,
                         unsigned short* __restrict__ hb, int n) {
  int i = blockIdx.x * 256 + threadIdx.x;
  if (i < n) {
    float v = a[i] + b[i] + c[i];
    h[i] = v;
    hb[i] = f2b(v);
  }
}

__global__ void k_zero_i(int* __restrict__ p, int n) {
  int i = blockIdx.x * 256 + threadIdx.x;
  if (i < n) p[i] = 0;
}

__global__ void k_copy_i(const int* __restrict__ a, int* __restrict__ b, int n) {
  int i = blockIdx.x * 256 + threadIdx.x;
  if (i < n) b[i] = a[i];
}

// ---------------- CSR build (combined, sorted by (dst, type)) ----------------
__global__ void k_deg(const int* __restrict__ e0, const int* __restrict__ e1,
                      const int* __restrict__ e2, const int* __restrict__ e3, int E, int N,
                      int* __restrict__ deg2) {
  int i = blockIdx.x * 256 + threadIdx.x;
  if (i >= 4 * E) return;
  int t = i / E, e = i - t * E;
  const int* ei = t == 0 ? e0 : t == 1 ? e1 : t == 2 ? e2 : e3;
  atomicAdd(&deg2[ei[E + e] * 4 + t], 1);
}

__global__ __launch_bounds__(256) void k_scan1(const int* __restrict__ in, int* __restrict__ out,
                                               int* __restrict__ bsum, int n, int nblk) {
  int b = blockIdx.x, tid = threadIdx.x;
  int idx0 = b * 1024 + tid * 4;
  int v[4], sum = 0;
#pragma unroll
  for (int j = 0; j < 4; ++j) {
    int ix = idx0 + j;
    v[j] = (ix < n) ? in[ix] : 0;
    sum += v[j];
  }
  __shared__ int sh[256];
  sh[tid] = sum;
  __syncthreads();
  for (int off = 1; off < 256; off <<= 1) {
    int t = 0;
    if (tid >= off) t = sh[tid - off];
    __syncthreads();
    sh[tid] += t;
    __syncthreads();
  }
  if (tid == 255) bsum[b] = sh[255];
  int run = (tid > 0) ? sh[tid - 1] : 0;
#pragma unroll
  for (int j = 0; j < 4; ++j) {
    int ix = idx0 + j;
    if (ix < n) out[ix] = run;
    run += v[j];
  }
}

__global__ void k_scan2b(int* __restrict__ bsum, int nblk) {
  __shared__ int sh[256];
  int tid = threadIdx.x;
  int v = (tid < nblk) ? bsum[tid] : 0;
  sh[tid] = v;
  __syncthreads();
  for (int off = 1; off < 256; off <<= 1) {
    int t = (tid >= off) ? sh[tid - off] : 0;
    __syncthreads();
    sh[tid] += t;
    __syncthreads();
  }
  if (tid < nblk) bsum[tid] = sh[tid] - v;
}

__global__ void k_scan3(int* __restrict__ out, const int* __restrict__ bsum, int n, int nblk) {
  int b = blockIdx.x;
  int add = bsum[b];
  int idx0 = b * 1024 + threadIdx.x * 4;
#pragma unroll
  for (int j = 0; j < 4; ++j) {
    int ix = idx0 + j;
    if (ix < n) out[ix] += add;
  }
}

__global__ void k_fill(const int* __restrict__ e0, const int* __restrict__ e1,
                       const int* __restrict__ e2, const int* __restrict__ e3, int E, int N,
                       int* __restrict__ next2, int* __restrict__ cs_src) {
  int i = blockIdx.x * 256 + threadIdx.x;
  if (i >= 4 * E) return;
  int t = i / E, e = i - t * E;
  const int* ei = t == 0 ? e0 : t == 1 ? e1 : t == 2 ? e2 : e3;
  int src = ei[e], dst = ei[E + e];
  int pos = atomicAdd(&next2[dst * 4 + t], 1);
  cs_src[pos] = src;
}

// ---------------- LDS staging helpers ----------------
__device__ __forceinline__ void stage_bf16_lds(short8* __restrict__ dst,
                                               const unsigned short* __restrict__ src, int row0,
                                               int N, int tid) {
  int r = tid >> 1, half = tid & 1;
  int grow = row0 + r;
  const short8* ap = (const short8*)(src + (size_t)grow * 128 + (half << 6));
#pragma unroll
  for (int j = 0; j < 8; ++j) {
    short8 pk = {0, 0, 0, 0, 0, 0, 0, 0};
    if (grow < N) pk = ap[j];
    int chunk = half * 8 + j;
    dst[r * 16 + (chunk ^ (r & 7))] = pk;
  }
}
__device__ __forceinline__ void stage_w_lds(short8* __restrict__ dst,
                                            const unsigned short* __restrict__ w, int tid) {
  int c = tid >> 1, half = tid & 1;
  const short8* wp = (const short8*)(w + (size_t)c * 128 + (half << 6));
#pragma unroll
  for (int j = 0; j < 8; ++j) {
    int chunk = half * 8 + j;
    dst[c * 16 + (chunk ^ (c & 7))] = wp[j];
  }
}

// ---------------- multi-weight MFMA GEMM ----------------
// A bf16 [N][128] (staged once if SAMEA); W = T tiles of [128][128] bf16 (row = out col).
// SUM=0: per-t bf16 out_t (+f32 bias_t). SUM=1: acc across t, single f32 write to o0.
template <int T, bool SAMEA, bool SUM>
__global__ __launch_bounds__(256) void k_gemm_multi(
    const unsigned short* __restrict__ A0, const unsigned short* __restrict__ A1,
    const unsigned short* __restrict__ A2, const unsigned short* __restrict__ A3,
    const unsigned short* __restrict__ W, const float* __restrict__ b0,
    const float* __restrict__ b1, const float* __restrict__ b2, const float* __restrict__ b3,
    void* __restrict__ o0, void* __restrict__ o1, void* __restrict__ o2, void* __restrict__ o3,
    int N) {
  __shared__ short8 As[2048];
  __shared__ short8 Bs[2048];
  const int tid = threadIdx.x;
  const int row0 = blockIdx.x * 128;
  const unsigned short* Aarr[4] = {A0, A1, A2, A3};
  const float* barr[4] = {b0, b1, b2, b3};
  void* oarr[4] = {o0, o1, o2, o3};
  const int w = tid >> 6, lane = tid & 63;
  const int wr = w >> 1, wc = w & 1;
  const int lr = lane & 15, lg = lane >> 4;
  if (SAMEA) stage_bf16_lds(As, A0, row0, N, tid);
  f32x4 acc[4][4];
#pragma unroll
  for (int i = 0; i < 4; ++i)
#pragma unroll
    for (int j = 0; j < 4; ++j) acc[i][j] = f32x4{0.f, 0.f, 0.f, 0.f};
#pragma unroll
  for (int t = 0; t < T; ++t) {
    if (t > 0) __syncthreads();
    if (!SAMEA) stage_bf16_lds(As, Aarr[t], row0, N, tid);
    stage_w_lds(Bs, W + (size_t)t * 16384, tid);
    __syncthreads();
    if (!SUM && t > 0) {
#pragma unroll
      for (int i = 0; i < 4; ++i)
#pragma unroll
        for (int j = 0; j < 4; ++j) acc[i][j] = f32x4{0.f, 0.f, 0.f, 0.f};
    }
#pragma unroll
    for (int ks = 0; ks < 4; ++ks) {
      short8 af[4], bfr[4];
#pragma unroll
      for (int rt = 0; rt < 4; ++rt) {
        int row = wr * 64 + rt * 16 + lr;
        af[rt] = As[row * 16 + ((ks * 4 + lg) ^ (row & 7))];
      }
#pragma unroll
      for (int ct = 0; ct < 4; ++ct) {
        int cc = wc * 64 + ct * 16 + lr;
        bfr[ct] = Bs[cc * 16 + ((ks * 4 + lg) ^ (cc & 7))];
      }
#pragma unroll
      for (int rt = 0; rt < 4; ++rt)
#pragma unroll
        for (int ct = 0; ct < 4; ++ct)
          acc[rt][ct] =
              __builtin_amdgcn_mfma_f32_16x16x32_bf16(af[rt], bfr[ct], acc[rt][ct], 0, 0, 0);
    }
    if (!SUM) {
      const float* bias = barr[t];
      unsigned short* out = (unsigned short*)oarr[t];
#pragma unroll
      for (int rt = 0; rt < 4; ++rt)
#pragma unroll
        for (int ct = 0; ct < 4; ++ct) {
          int col = wc * 64 + ct * 16 + lr;
          float bv = bias ? bias[col] : 0.f;
#pragma unroll
          for (int j = 0; j < 4; ++j) {
            int row = row0 + wr * 64 + rt * 16 + lg * 4 + j;
            if (row < N) out[(size_t)row * 128 + col] = f2b(acc[rt][ct][j] + bv);
          }
        }
    }
  }
  if (SUM) {
    float* out = (float*)o0;
#pragma unroll
    for (int rt = 0; rt < 4; ++rt)
#pragma unroll
      for (int ct = 0; ct < 4; ++ct) {
        int col = wc * 64 + ct * 16 + lr;
#pragma unroll
        for (int j = 0; j < 4; ++j) {
          int row = row0 + wr * 64 + rt * 16 + lg * 4 + j;
          if (row < N) out[(size_t)row * 128 + col] = acc[rt][ct][j];
        }
      }
  }
}

// single-tile GEMM: f32 A -> gelu -> bf16, @W +bias -> f32 out
__global__ __launch_bounds__(256) void k_gemm_gelu(const float* __restrict__ A,
                                                   const unsigned short* __restrict__ W,
                                                   const float* __restrict__ bias,
                                                   float* __restrict__ Cout, int N) {
  __shared__ short8 As[2048];
  __shared__ short8 Bs[2048];
  const int tid = threadIdx.x;
  const int row0 = blockIdx.x * 128;
  {
    int r = tid >> 1, half = tid & 1;
    int grow = row0 + r;
    bool ok = grow < N;
    const float* ap = A + (size_t)grow * 128 + half * 64;
#pragma unroll
    for (int j = 0; j < 8; ++j) {
      short8 pk = {0, 0, 0, 0, 0, 0, 0, 0};
      if (ok) {
        float4 v0 = ((const float4*)ap)[2 * j];
        float4 v1 = ((const float4*)ap)[2 * j + 1];
        float f[8] = {v0.x, v0.y, v0.z, v0.w, v1.x, v1.y, v1.z, v1.w};
#pragma unroll
        for (int q = 0; q < 8; ++q) pk[q] = (short)f2b(gelu_f(f[q]));
      }
      int chunk = half * 8 + j;
      As[r * 16 + (chunk ^ (r & 7))] = pk;
    }
  }
  stage_w_lds(Bs, W, tid);
  __syncthreads();
  const int w = tid >> 6, lane = tid & 63;
  const int wr = w >> 1, wc = w & 1;
  const int lr = lane & 15, lg = lane >> 4;
  f32x4 acc[4][4];
#pragma unroll
  for (int i = 0; i < 4; ++i)
#pragma unroll
    for (int j = 0; j < 4; ++j) acc[i][j] = f32x4{0.f, 0.f, 0.f, 0.f};
#pragma unroll
  for (int ks = 0; ks < 4; ++ks) {
    short8 af[4], bfr[4];
#pragma unroll
    for (int rt = 0; rt < 4; ++rt) {
      int row = wr * 64 + rt * 16 + lr;
      af[rt] = As[row * 16 + ((ks * 4 + lg) ^ (row & 7))];
    }
#pragma unroll
    for (int ct = 0; ct < 4; ++ct) {
      int cc = wc * 64 + ct * 16 + lr;
      bfr[ct] = Bs[cc * 16 + ((ks * 4 + lg) ^ (cc & 7))];
    }
#pragma unroll
    for (int rt = 0; rt < 4; ++rt)
#pragma unroll
      for (int ct = 0; ct < 4; ++ct)
        acc[rt][ct] =
            __builtin_amdgcn_mfma_f32_16x16x32_bf16(af[rt], bfr[ct], acc[rt][ct], 0, 0, 0);
  }
#pragma unroll
  for (int rt = 0; rt < 4; ++rt)
#pragma unroll
    for (int ct = 0; ct < 4; ++ct) {
      int col = wc * 64 + ct * 16 + lr;
      float bv = bias[col];
#pragma unroll
      for (int j = 0; j < 4; ++j) {
        int row = row0 + wr * 64 + rt * 16 + lg * 4 + j;
        if (row < N) Cout[(size_t)row * 128 + col] = acc[rt][ct][j] + bv;
      }
    }
}

// ---------------- weight converters ----------------
// Wbt[(t*128+n)][k] = W_t[k][n]
__global__ void k_cvtW(const float* __restrict__ W0, const float* __restrict__ W1,
                       const float* __restrict__ W2, const float* __restrict__ W3, int ntile,
                       unsigned short* __restrict__ out) {
  int i = blockIdx.x * 256 + threadIdx.x;
  if (i >= ntile * 16384) return;
  int t = i >> 14, r = i & 16383;
  int n = r >> 7, k = r & 127;
  const float* W = t == 0 ? W0 : t == 1 ? W1 : t == 2 ? W2 : W3;
  out[i] = f2b(W[k * 128 + n]);
}

// block-diagonal rel weight. TRANS=false (mrel): W[c=h*16+f][k=h*16+d]=rel[t,h,d,f]
//                            TRANS=true  (arel): W[c=h*16+d][k=h*16+f]=rel[t,h,d,f]
template <bool TRANS>
__global__ void k_cvt_bd(const float* __restrict__ rel4, unsigned short* __restrict__ Wo) {
  int i = blockIdx.x * 256 + threadIdx.x;
  if (i >= 4 * 16384) return;
  int t = i >> 14, r = i & 16383;
  int c = r >> 7, k = r & 127;
  int hc = c >> 4, cc = c & 15, hk = k >> 4, kk = k & 15;
  float v = 0.f;
  if (hc == hk) v = rel4[t * 2048 + hc * 256 + (TRANS ? (cc * 16 + kk) : (kk * 16 + cc))];
  Wo[i] = f2b(v);
}

// ---------------- GAT ----------------
__global__ void k_alar4(const unsigned short* __restrict__ xwb4, const float* __restrict__ as_,
                        const float* __restrict__ ad_, unsigned short* __restrict__ al4,
                        unsigned short* __restrict__ ar4, int N) {
  int i = blockIdx.x * 256 + threadIdx.x;
  if (i >= 4 * N * 8) return;
  int t = i / (N * 8), r = i - t * (N * 8);
  int n = r >> 3, h = r & 7;
  float x[16];
  ldbf16x16(xwb4 + ((size_t)t * N + n) * 128 + h * 16, x);
  float sa = 0.f, sd = 0.f;
#pragma unroll
  for (int j = 0; j < 16; ++j) {
    sa += x[j] * as_[t * 128 + h * 16 + j];
    sd += x[j] * ad_[t * 128 + h * 16 + j];
  }
  al4[i] = f2b(sa);
  ar4[i] = f2b(sd);
}

// fused 4-type GAT aggregation: one dispatch per layer, acc written once
__global__ __launch_bounds__(256) void k_gat_agg4(const int* __restrict__ base2,
                                                  const int* __restrict__ cs_src,
                                                  const unsigned short* __restrict__ al4,
                                                  const unsigned short* __restrict__ ar4,
                                                  const unsigned short* __restrict__ xwb4,
                                                  const float* __restrict__ bias,
                                                  float* __restrict__ acc, int N, int fourE) {
  int n = blockIdx.x * 2 + (threadIdx.x >> 7);
  if (n >= N) return;
  int h = (threadIdx.x >> 4) & 7, f = threadIdx.x & 15;
  int hf = h * 16 + f;
  float total = bias[hf] + bias[128 + hf] + bias[256 + hf] + bias[384 + hf];
#pragma unroll
  for (int t = 0; t < 4; ++t) {
    const unsigned short* xw = xwb4 + (size_t)t * N * 128;
    size_t alo = (size_t)t * N * 8;
    int idx = n * 4 + t;
    int rs = base2[idx];
    int re = (idx + 1 < 4 * N) ? base2[idx + 1] : fourE;
    float arn = b2f(ar4[alo + (size_t)n * 8 + h]);
    float xs = lrelu_f(b2f(al4[alo + (size_t)n * 8 + h]) + arn);
    float m = xs, s = 1.f;
    float accf = b2f(xw[(size_t)n * 128 + hf]);
    for (int i = rs; i < re; i += 4) {
      int cnt = re - i;
      int sj[4];
      float aj[4], vj[4];
#pragma unroll
      for (int j = 0; j < 4; ++j) sj[j] = (j < cnt) ? cs_src[i + j] : 0;
#pragma unroll
      for (int j = 0; j < 4; ++j) aj[j] = b2f(al4[alo + (size_t)sj[j] * 8 + h]);
#pragma unroll
      for (int j = 0; j < 4; ++j) vj[j] = b2f(xw[(size_t)sj[j] * 128 + hf]);
#pragma unroll
      for (int j = 0; j < 4; ++j) {
        float x = (j < cnt) ? lrelu_f(aj[j] + arn) : -3.0e38f;
        float mn = fmaxf(m, x);
        float rr = __expf(m - mn);
        float p = __expf(x - mn);
        s = s * rr + p;
        accf = accf * rr + p * vj[j];
        m = mn;
      }
    }
    total += accf / s;
  }
  acc[(size_t)n * 128 + hf] = total;
}

// ---------------- fused residual + RMSNorm + GELU (+bf16 copy) ----------------
template <bool MIX, bool WB>
__global__ __launch_bounds__(256) void k_norm(const float* __restrict__ hin,
                                              const float* __restrict__ o_,
                                              const float* __restrict__ g,
                                              const float* __restrict__ skip,
                                              float* __restrict__ hout,
                                              unsigned short* __restrict__ hb, int N) {
  int w = threadIdx.x >> 6, lane = threadIdx.x & 63;
  int row = blockIdx.x * 4 + w;
  if (row >= N) return;
  size_t base = (size_t)row * D;
  float h0 = hin[base + lane], h1 = hin[base + 64 + lane];
  float o0 = o_[base + lane], o1 = o_[base + 64 + lane];
  if (MIX) {
    float beta = 1.f / (1.f + expf(-skip[0]));
    o0 = beta * o0 + (1.f - beta) * h0;
    o1 = beta * o1 + (1.f - beta) * h1;
  }
  float ss = o0 * o0 + o1 * o1;
#pragma unroll
  for (int msk = 1; msk < 64; msk <<= 1) ss += __shfl_xor(ss, msk, 64);
  float r = rsqrtf(ss * (1.f / 128.f) + 1e-6f);
  float y0 = gelu_f(h0 + g[lane] * o0 * r);
  float y1 = gelu_f(h1 + g[64 + lane] * o1 * r);
  hout[base + lane] = y0;
  hout[base + 64 + lane] = y1;
  if (WB) {
    hb[base + lane] = f2b(y0);
    hb[base + 64 + lane] = f2b(y1);
  }
}

// ---------------- HGT ----------------
// fused logits + joint online softmax reduce per (n,h); att <- raw logits (bf16)
__global__ void k_hgt_logits(const int* __restrict__ base2, const int* __restrict__ cs_src,
                             const unsigned short* __restrict__ kb,
                             const unsigned short* __restrict__ qa0,
                             const unsigned short* __restrict__ qa1,
                             const unsigned short* __restrict__ qa2,
                             const unsigned short* __restrict__ qa3,
                             const float* __restrict__ prel, unsigned short* __restrict__ att,
                             float* __restrict__ mden, float* __restrict__ sinv, int N,
                             int fourE) {
  int i = blockIdx.x * 256 + threadIdx.x;
  if (i >= N * 8) return;
  int n = i >> 3, h = i & 7;
  const unsigned short* qas[4] = {qa0, qa1, qa2, qa3};
  float m = -3.0e38f, s = 0.f;
#pragma unroll
  for (int t = 0; t < 4; ++t) {
    float qf[16];
    ldbf16x16(qas[t] + (size_t)n * 128 + h * 16, qf);
    float pr = prel[t * 8 + h] * 0.25f;
    int idx = n * 4 + t;
    int rs = base2[idx];
    int re = (idx + 1 < 4 * N) ? base2[idx + 1] : fourE;
    for (int e = rs; e < re; ++e) {
      int src = cs_src[e];
      float kf[16];
      ldbf16x16(kb + (size_t)src * 128 + h * 16, kf);
      float a = 0.f;
#pragma unroll
      for (int j = 0; j < 16; ++j) a += kf[j] * qf[j];
      a *= pr;
      unsigned short ab = f2b(a);
      att[(size_t)e * 8 + h] = ab;
      float a2 = b2f(ab);
      float mn = fmaxf(m, a2);
      s = s * __expf(m - mn) + __expf(a2 - mn);
      m = mn;
    }
  }
  mden[i] = m;
  sinv[i] = s > 0.f ? 1.f / s : 0.f;
}

// per-type weighted v gather-sum -> aggT4 bf16
__global__ __launch_bounds__(256) void k_hgt_agg4(const int* __restrict__ base2,
                                                  const int* __restrict__ cs_src,
                                                  const unsigned short* __restrict__ att,
                                                  const float* __restrict__ mden,
                                                  const float* __restrict__ sinv,
                                                  const unsigned short* __restrict__ vb,
                                                  unsigned short* __restrict__ aggT4, int N,
                                                  int fourE) {
  int n = blockIdx.x * 2 + (threadIdx.x >> 7);
  if (n >= N) return;
  int h = (threadIdx.x >> 4) & 7, f = threadIdx.x & 15;
  int hf = h * 16 + f;
  float m = mden[n * 8 + h], inv = sinv[n * 8 + h];
#pragma unroll
  for (int t = 0; t < 4; ++t) {
    int idx = n * 4 + t;
    int rs = base2[idx];
    int re = (idx + 1 < 4 * N) ? base2[idx + 1] : fourE;
    float sum = 0.f;
    for (int i = rs; i < re; i += 4) {
      int cnt = re - i;
      int sj[4];
      float aj[4], vj[4];
#pragma unroll
      for (int j = 0; j < 4; ++j) sj[j] = (j < cnt) ? cs_src[i + j] : 0;
#pragma unroll
      for (int j = 0; j < 4; ++j) aj[j] = (j < cnt) ? b2f(att[(size_t)(i + j) * 8 + h]) : -3.0e38f;
#pragma unroll
      for (int j = 0; j < 4; ++j) vj[j] = b2f(vb[(size_t)sj[j] * 128 + hf]);
#pragma unroll
      for (int j = 0; j < 4; ++j) sum += __expf(aj[j] - m) * vj[j];
    }
    aggT4[(size_t)t * N * 128 + (size_t)n * 128 + hf] = f2b(sum * inv);
  }
}

// ---------------- host side ----------------
extern "C" void kernel_launch(void* const* d_in, const int* in_sizes, int n_in, void* d_out,
                              int out_size, void* d_ws, size_t ws_size, hipStream_t stream) {
  const float* zL = (const float*)d_in[0];
  const float* zH = (const float*)d_in[1];
  const float* xe = (const float*)d_in[2];
  const float* W1 = (const float*)d_in[3];
  const float* as1 = (const float*)d_in[4];
  const float* ad1 = (const float*)d_in[5];
  const float* b1 = (const float*)d_in[6];
  const float* W2 = (const float*)d_in[7];
  const float* as2 = (const float*)d_in[8];
  const float* ad2 = (const float*)d_in[9];
  const float* b2 = (const float*)d_in[10];
  const float* Wk = (const float*)d_in[11];
  const float* bk = (const float*)d_in[12];
  const float* Wq = (const float*)d_in[13];
  const float* bq = (const float*)d_in[14];
  const float* Wv = (const float*)d_in[15];
  const float* bv = (const float*)d_in[16];
  const float* arel = (const float*)d_in[17];
  const float* mrel = (const float*)d_in[18];
  const float* prel = (const float*)d_in[19];
  const float* Wo = (const float*)d_in[20];
  const float* bo = (const float*)d_in[21];
  const float* skip = (const float*)d_in[22];
  const float* g1 = (const float*)d_in[23];
  const float* g2 = (const float*)d_in[24];
  const float* g3 = (const float*)d_in[25];
  const int* ei[4] = {(const int*)d_in[26], (const int*)d_in[27], (const int*)d_in[28],
                      (const int*)d_in[29]};

  const int N = in_sizes[0] / D;   // 50000
  const int E = in_sizes[26] / 2;  // 150000
  const int fourE = 4 * E;
  const int fourN = 4 * N;
  const size_t ND_ = (size_t)N * D;  // 6.4M
  (void)ws_size; (void)n_in; (void)out_size;

  float* h = (float*)d_out;
  float* ws = (float*)d_ws;
  size_t o = 0;
  float* acc = ws + o; o += ND_;                                  // 25.6MB: GAT acc / qa3 / chain out
  unsigned short* RegA = (unsigned short*)(ws + o); o += 2 * ND_; // 51.2MB: xwb4 / kb,qb,qa / aggT4 / out2
  unsigned short* hb = (unsigned short*)(ws + o); o += ND_ / 2;   // 12.8MB: hb / vb
  unsigned short* attb = (unsigned short*)(ws + o); o += (size_t)fourE * 4;  // 9.6MB
  unsigned short* al4 = (unsigned short*)(ws + o); o += (size_t)fourN * 4;   // 3.2MB (4N*8 bf16; f32 mden overlay)
  unsigned short* ar4 = (unsigned short*)(ws + o); o += (size_t)fourN * 4;   // 3.2MB (4N*8 bf16; f32 sinv overlay)
  unsigned short* Wbt = (unsigned short*)(ws + o); o += 32768;
  unsigned short* Wad = (unsigned short*)(ws + o); o += 32768;
  unsigned short* Wbd = (unsigned short*)(ws + o); o += 32768;
  int* ib = (int*)(ws + o);
  size_t io = 0;
  int* deg2 = ib + io; io += fourN;
  int* base2 = ib + io; io += fourN;
  int* next2 = ib + io; io += fourN;
  int* bsum = ib + io; io += 256;
  int* cs_src = ib + io; io += fourE;

  unsigned short* s0 = RegA;
  unsigned short* s1 = RegA + ND_;
  unsigned short* s2 = RegA + 2 * ND_;
  unsigned short* s3 = RegA + 3 * ND_;
  unsigned short* accU = (unsigned short*)acc;  // qa slot 3 overlay

  const int nd = (int)ND_;
  const int nb128 = (N + 127) / 128;
  const int nblk4 = (fourN + 1023) / 1024;

  k_init_h<<<(nd + 255) / 256, 256, 0, stream>>>(zL, zH, xe, h, hb, nd);

  // ---- CSR (combined, (dst,type)-sorted; reused by all layers) ----
  k_zero_i<<<(fourN + 255) / 256, 256, 0, stream>>>(deg2, fourN);
  k_deg<<<(fourE + 255) / 256, 256, 0, stream>>>(ei[0], ei[1], ei[2], ei[3], E, N, deg2);
  k_scan1<<<nblk4, 256, 0, stream>>>(deg2, base2, bsum, fourN, nblk4);
  k_scan2b<<<1, 256, 0, stream>>>(bsum, nblk4);
  k_scan3<<<nblk4, 256, 0, stream>>>(base2, bsum, fourN, nblk4);
  k_copy_i<<<(fourN + 255) / 256, 256, 0, stream>>>(base2, next2, fourN);
  k_fill<<<(fourE + 255) / 256, 256, 0, stream>>>(ei[0], ei[1], ei[2], ei[3], E, N, next2, cs_src);

  // ---- GAT layers ----
  const float* Ws[2] = {W1, W2};
  const float* ass[2] = {as1, as2};
  const float* ads[2] = {ad1, ad2};
  const float* bs[2] = {b1, b2};
  const float* gs[2] = {g1, g2};
  for (int L = 0; L < 2; ++L) {
    const float* Wt = Ws[L];
    k_cvtW<<<(4 * 16384 + 255) / 256, 256, 0, stream>>>(Wt, Wt + 16384, Wt + 32768, Wt + 49152, 4,
                                                        Wbt);
    k_gemm_multi<4, true, false><<<nb128, 256, 0, stream>>>(
        hb, hb, hb, hb, Wbt, nullptr, nullptr, nullptr, nullptr, s0, s1, s2, s3, N);
    k_alar4<<<(4 * N * 8 + 255) / 256, 256, 0, stream>>>(RegA, ass[L], ads[L], al4, ar4, N);
    k_gat_agg4<<<(N + 1) / 2, 256, 0, stream>>>(base2, cs_src, al4, ar4, RegA, bs[L], acc, N,
                                                fourE);
    k_norm<false, true><<<(N + 3) / 4, 256, 0, stream>>>(h, acc, gs[L], nullptr, h, hb, N);
  }

  // ---- HGT ----
  // k,q,v GEMM: A=hb staged once; vb overlays hb (each block writes only its own staged rows)
  unsigned short* kb = s0;
  unsigned short* qb = s1;
  unsigned short* vb = hb;
  k_cvtW<<<(3 * 16384 + 255) / 256, 256, 0, stream>>>(Wk, Wq, Wv, Wv, 3, Wbt);
  k_gemm_multi<3, true, false><<<nb128, 256, 0, stream>>>(hb, hb, hb, hb, Wbt, bk, bq, bv,
                                                          nullptr, kb, qb, vb, nullptr, N);
  // qa_t = q @ arel_t^T (block-diagonal); outs overlay qb,s2,s3,acc
  k_cvt_bd<true><<<(4 * 16384 + 255) / 256, 256, 0, stream>>>(arel, Wad);
  k_gemm_multi<4, true, false><<<nb128, 256, 0, stream>>>(
      qb, qb, qb, qb, Wad, nullptr, nullptr, nullptr, nullptr, s1, s2, s3, accU, N);
  // fused logits + joint softmax reduction
  float* mden = (float*)al4;
  float* sinv = (float*)ar4;
  k_hgt_logits<<<(N * 8 + 255) / 256, 256, 0, stream>>>(base2, cs_src, kb, s1, s2, s3, accU, prel,
                                                        attb, mden, sinv, N, fourE);
  // per-type weighted v sums (aggT4 overwrites RegA; kb/q* dead)
  k_hgt_agg4<<<(N + 1) / 2, 256, 0, stream>>>(base2, cs_src, attb, mden, sinv, vb, RegA, N, fourE);
  // chain: acc = sum_t aggT_t @ mrel_t (block-diagonal), single write
  k_cvt_bd<false><<<(4 * 16384 + 255) / 256, 256, 0, stream>>>(mrel, Wbd);
  k_gemm_multi<4, false, true><<<nb128, 256, 0, stream>>>(
      s0, s1, s2, s3, Wbd, nullptr, nullptr, nullptr, nullptr, acc, nullptr, nullptr, nullptr, N);
  // out2 = gelu(acc) @ Wo + bo -> f32 (overlays RegA; aggT dead)
  float* out2 = (float*)RegA;
  k_cvtW<<<(16384 + 255) / 256, 256, 0, stream>>>(Wo, Wo, Wo, Wo, 1, Wbt);
  k_gemm_gelu<<<nb128, 256, 0, stream>>>(acc, Wbt, bo, out2, N);
  k_norm<true, false><<<(N + 3) / 4, 256, 0, stream>>>(h, out2, g3, skip, (float*)d_out, nullptr,
                                                       N);
}